// Round 14
// baseline (395.998 us; speedup 1.0000x reference)
//
#include <hip/hip_runtime.h>

#define BATCH   2
#define LSEQ    4096
#define DMODEL  1024
#define DINNER  2048
#define NHEADS  16
#define DSTATE  64
#define HEADDIM 128
#define ZDIM    4112
#define BLROWS  (BATCH*LSEQ)   // 8192
#define QCHUNK  64
#define NCHUNK  (LSEQ/QCHUNK)  // 64
#define UPAD    1088           // padded K-stride for u_bf / Wt_f rows
#define GPAD    2112           // padded K-stride for yn(g) / Wt_o rows

#define AS1 __attribute__((address_space(1)))
#define AS3 __attribute__((address_space(3)))

typedef __bf16 bf16;
typedef __bf16 bf16x8 __attribute__((ext_vector_type(8)));
typedef __bf16 bf16x4 __attribute__((ext_vector_type(4)));
typedef float  f32x4  __attribute__((ext_vector_type(4)));

// paired-row LDS swizzle for [R rows][32 bf16] regions (verified conflict-free rounds 8-13)
__device__ __forceinline__ int lds_elem(int row, int c)
{
    return (row >> 1) * 64 + (row & 1) * 32 + (((c ^ ((row >> 1) & 3)) & 3) << 3);
}

// ---------------- fp32 -> bf16 convert with padded row stride ----------------
__global__ void cvt_pad_kernel(const float* __restrict__ in, bf16* __restrict__ out)
{
    int gid = blockIdx.x * 256 + threadIdx.x;   // 8192 rows x 256 quads
    int row = gid >> 8, c4 = (gid & 255) * 4;
    float4 v = *reinterpret_cast<const float4*>(in + (size_t)row * DMODEL + c4);
    bf16x4 o;
    o[0] = (bf16)v.x; o[1] = (bf16)v.y; o[2] = (bf16)v.z; o[3] = (bf16)v.w;
    *reinterpret_cast<bf16x4*>(out + (size_t)row * UPAD + c4) = o;
}

// ---------------- transpose + convert: src[R][C] f32 -> dst[Cpad rows][stride dstS] bf16 ----
__global__ void transpose_cvt_kernel(const float* __restrict__ src, bf16* __restrict__ dst,
                                     int R, int C, int Cpad, int dstS)
{
    __shared__ float tile[32][33];
    int tx = threadIdx.x;   // 0..31
    int ty = threadIdx.y;   // 0..7
    int c0 = blockIdx.x * 32;
    int r0 = blockIdx.y * 32;
#pragma unroll
    for (int q = 0; q < 4; q++) {
        int r = r0 + ty + q * 8;
        int c = c0 + tx;
        float v = 0.f;
        if (r < R && c < C) v = src[(size_t)r * C + c];
        tile[ty + q * 8][tx] = v;
    }
    __syncthreads();
#pragma unroll
    for (int q = 0; q < 4; q++) {
        int oc = c0 + ty + q * 8;   // output row (= original col)
        int orr = r0 + tx;          // output col (= original row)
        if (oc < Cpad && orr < R)
            dst[(size_t)oc * dstS + orr] = (bf16)tile[tx][ty + q * 8];
    }
}

// ======= fused GEMM, 256x128 tile: 4 waves of 128x64, BK=32 dbuf, 48KB LDS =======
// Wave reads 12 b128 per K-step for 32 MFMA (384 B/MFMA, -25% LDS-port vs 128^2 tile).
// Schedule per phase (verified rounds 11-13): ds_read(slot p) ; lgkm(0) ; barrier ;
// STAGE(p+2) ; MFMA ; vmcnt(6) ; barrier. XCD supertile: 4 bm rows/XCD, bn bm-fast.
template<int NSLICE, int KROW, int NBN>
__global__ __launch_bounds__(256) void gemm_w128_kernel(
    const bf16* __restrict__ A, const bf16* __restrict__ Bt,
    bf16* __restrict__ z, bf16* __restrict__ g, float* __restrict__ dtout)
{
    constexpr int SLOTSZ = 12288;                  // A 8192 + B 4096 bf16
    __shared__ __align__(16) bf16 lds[2 * SLOTSZ]; // 48 KB
    const int tid = threadIdx.x;
    const int lane = tid & 63, wid = tid >> 6;
    const int wm = (wid >> 1) * 128, wn = (wid & 1) * 64;
    const int lml = lane & 15, kc = lane >> 4;

    // XCD supertile: grid = 32 bm x NBN bn (divisible by 8)
    const int bid = blockIdx.x;
    const int xcd = bid & 7;
    const int idx = bid >> 3;
    const int bm = xcd * 4 + (idx & 3);
    const int bn = idx >> 2;

    const bf16* Abase = A + (size_t)(bm * 256) * KROW;
    const bf16* Bbase = Bt + (size_t)(bn * 128) * KROW;

#define STAGEW(pp) do {                                                                  \
    const int _p = (pp); const int _slot = _p & 1; const size_t _ko = (size_t)_p * 32;   \
    _Pragma("unroll") for (int it = 0; it < 6; ++it) {                                   \
        int q = it * 256 + tid;            /* 0..1023 A-chunks, 1024..1535 B-chunks */   \
        int o = (q < 1024) ? q : q - 1024;                                               \
        int prow = o >> 3, wi = o & 7;                                                   \
        int row = prow * 2 + (wi >> 2), c = (wi & 3) ^ (prow & 3);                       \
        const bf16* _src = ((q < 1024) ? Abase : Bbase) + (size_t)row * KROW + _ko + c * 8; \
        int _dst = _slot * SLOTSZ + ((q < 1024) ? 0 : 8192) + o * 8;                     \
        __builtin_amdgcn_global_load_lds((const AS1 void*)_src,                          \
            (AS3 void*)(&lds[_dst]), 16, 0, 0);                                          \
    }                                                                                    \
} while (0)

    f32x4 acc[8][4];
#pragma unroll
    for (int i = 0; i < 8; i++)
#pragma unroll
        for (int j = 0; j < 4; j++) acc[i][j] = (f32x4){0.f, 0.f, 0.f, 0.f};

    STAGEW(0); STAGEW(1);
    asm volatile("s_waitcnt vmcnt(6)" ::: "memory");   // slot 0 landed (slot 1 in flight)
    __builtin_amdgcn_s_barrier();

    for (int p = 0; p < NSLICE; ++p) {
        const bf16* base_ = &lds[(p & 1) * SLOTSZ];
        bf16x8 af[8], bfv[4];
#pragma unroll
        for (int i = 0; i < 8; ++i) {
            int row = wm + i * 16 + lml;
            af[i] = *reinterpret_cast<const bf16x8*>(&base_[lds_elem(row, kc)]);
        }
#pragma unroll
        for (int j = 0; j < 4; ++j) {
            int row = wn + j * 16 + lml;
            bfv[j] = *reinterpret_cast<const bf16x8*>(&base_[8192 + lds_elem(row, kc)]);
        }
        asm volatile("s_waitcnt lgkmcnt(0)" ::: "memory");
        __builtin_amdgcn_sched_barrier(0);
        __builtin_amdgcn_s_barrier();        // slot p fully consumed by all waves
        if (p + 2 < NSLICE) STAGEW(p + 2);   // overwrite slot p&1
        __builtin_amdgcn_sched_barrier(0);
        __builtin_amdgcn_s_setprio(1);
#pragma unroll
        for (int i = 0; i < 8; ++i)
#pragma unroll
            for (int j = 0; j < 4; ++j)
                acc[i][j] = __builtin_amdgcn_mfma_f32_16x16x32_bf16(af[i], bfv[j], acc[i][j], 0, 0, 0);
        __builtin_amdgcn_s_setprio(0);
        if (p + 1 < NSLICE) {
            if (p + 2 < NSLICE) { asm volatile("s_waitcnt vmcnt(6)" ::: "memory"); }
            else { asm volatile("s_waitcnt vmcnt(0)" ::: "memory"); }
            __builtin_amdgcn_s_barrier();
        }
    }
#undef STAGEW

    const int rbase = (lane >> 4) * 4;
#pragma unroll
    for (int i = 0; i < 8; i++) {
#pragma unroll
        for (int j = 0; j < 4; j++) {
            int col = bn * 128 + wn + j * 16 + lml;
            bool isZ = (col < ZDIM);
            bool isG = (col >= 4224) && (col < 4224 + DINNER);
            bool isDT = (col >= 4096) && (col < ZDIM);
            if (!isZ && !isG) continue;
#pragma unroll
            for (int r = 0; r < 4; r++) {
                int row = bm * 256 + wm + i * 16 + rbase + r;
                float v = acc[i][j][r];
                if (isZ) {
                    z[(size_t)row * ZDIM + col] = (bf16)v;
                    if (isDT) dtout[(size_t)row * NHEADS + (col - 4096)] = v;
                } else {
                    g[(size_t)row * GPAD + (col - 4224)] = (bf16)v;
                }
            }
        }
    }
}

// ======= dbuf GEMM (round-11/13 config): 128x128, 4 waves, K-slices 32 — out GEMM =======
template<int NSLICE, int KROW, int NBN>
__global__ __launch_bounds__(256) void gemm_db_kernel(
    const bf16* __restrict__ A, const bf16* __restrict__ Bt, float* __restrict__ c32)
{
    constexpr int SLOTSZ = 256 * 32;
    __shared__ __align__(16) bf16 lds[2 * SLOTSZ];   // 32 KB
    const int tid = threadIdx.x;
    const int lane = tid & 63, wid = tid >> 6;
    const int wm = (wid >> 1) * 64, wn = (wid & 1) * 64;
    const int lml = lane & 15, kc = lane >> 4;

    const int bid = blockIdx.x;
    const int xcd = bid & 7;
    const int idx = bid >> 3;
    const int bm = xcd * 8 + (idx & 7);
    const int bn = idx >> 3;

    const bf16* Abase = A + (size_t)(bm * 128) * KROW;
    const bf16* Bbase = Bt + (size_t)(bn * 128) * KROW;

#define STAGE8(pp) do {                                                                  \
    const int _p = (pp); const int _slot = _p & 1; const size_t _ko = (size_t)_p * 32;   \
    _Pragma("unroll") for (int it = 0; it < 4; ++it) {                                   \
        int q = it * 256 + tid;                                                          \
        int o = (q < 512) ? q : q - 512;                                                 \
        int prow = o >> 3, wi = o & 7;                                                   \
        int row = prow * 2 + (wi >> 2), c = (wi & 3) ^ (prow & 3);                       \
        const bf16* _src = ((q < 512) ? Abase : Bbase) + (size_t)row * KROW + _ko + c * 8; \
        int _dst = _slot * SLOTSZ + ((q < 512) ? 0 : 4096) + o * 8;                      \
        __builtin_amdgcn_global_load_lds((const AS1 void*)_src,                          \
            (AS3 void*)(&lds[_dst]), 16, 0, 0);                                          \
    }                                                                                    \
} while (0)

    f32x4 acc[4][4];
#pragma unroll
    for (int i = 0; i < 4; i++)
#pragma unroll
        for (int j = 0; j < 4; j++) acc[i][j] = (f32x4){0.f, 0.f, 0.f, 0.f};

    STAGE8(0); STAGE8(1);
    asm volatile("s_waitcnt vmcnt(4)" ::: "memory");
    __builtin_amdgcn_s_barrier();

    for (int p = 0; p < NSLICE; ++p) {
        const bf16* base_ = &lds[(p & 1) * SLOTSZ];
        bf16x8 af[4], bfv[4];
#pragma unroll
        for (int i = 0; i < 4; ++i) {
            int row = wm + i * 16 + lml;
            af[i] = *reinterpret_cast<const bf16x8*>(&base_[lds_elem(row, kc)]);
        }
#pragma unroll
        for (int j = 0; j < 4; ++j) {
            int row = wn + j * 16 + lml;
            bfv[j] = *reinterpret_cast<const bf16x8*>(&base_[4096 + lds_elem(row, kc)]);
        }
        asm volatile("s_waitcnt lgkmcnt(0)" ::: "memory");
        __builtin_amdgcn_sched_barrier(0);
        __builtin_amdgcn_s_barrier();
        if (p + 2 < NSLICE) STAGE8(p + 2);
        __builtin_amdgcn_sched_barrier(0);
        __builtin_amdgcn_s_setprio(1);
#pragma unroll
        for (int i = 0; i < 4; ++i)
#pragma unroll
            for (int j = 0; j < 4; ++j)
                acc[i][j] = __builtin_amdgcn_mfma_f32_16x16x32_bf16(af[i], bfv[j], acc[i][j], 0, 0, 0);
        __builtin_amdgcn_s_setprio(0);
        if (p + 1 < NSLICE) {
            if (p + 2 < NSLICE) { asm volatile("s_waitcnt vmcnt(4)" ::: "memory"); }
            else { asm volatile("s_waitcnt vmcnt(0)" ::: "memory"); }
            __builtin_amdgcn_s_barrier();
        }
    }
#undef STAGE8

    const int rbase = (lane >> 4) * 4;
#pragma unroll
    for (int i = 0; i < 4; i++) {
#pragma unroll
        for (int j = 0; j < 4; j++) {
            int col = bn * 128 + wn + j * 16 + lml;
#pragma unroll
            for (int r = 0; r < 4; r++) {
                int row = bm * 128 + wm + i * 16 + rbase + r;
                c32[(size_t)row * 1024 + col] = acc[i][j][r];
            }
        }
    }
}

// ---------------- causal depthwise conv (D_CONV=4) + SiLU, bf16x8 vectorized ----------------
__global__ void conv_silu_kernel(const bf16* __restrict__ z, const float* __restrict__ conv_w,
                                 const float* __restrict__ conv_b, bf16* __restrict__ x)
{
    int gid = blockIdx.x * 256 + threadIdx.x;   // one thread per 8 channels
    if (gid >= BLROWS * (DINNER / 8)) return;
    int c0 = (gid & 255) * 8;
    int bl = gid >> 8;
    int l = bl & (LSEQ - 1);
    float4 wv[8];
#pragma unroll
    for (int e = 0; e < 8; e++) wv[e] = *reinterpret_cast<const float4*>(conv_w + (size_t)(c0 + e) * 4);
    float a8[8];
    {
        float4 b0 = *reinterpret_cast<const float4*>(conv_b + c0);
        float4 b1 = *reinterpret_cast<const float4*>(conv_b + c0 + 4);
        a8[0] = b0.x; a8[1] = b0.y; a8[2] = b0.z; a8[3] = b0.w;
        a8[4] = b1.x; a8[5] = b1.y; a8[6] = b1.z; a8[7] = b1.w;
    }
#pragma unroll
    for (int k = 0; k < 4; k++) {
        if (l - 3 + k >= 0) {
            bf16x8 zv = *reinterpret_cast<const bf16x8*>(z + (size_t)(bl - 3 + k) * ZDIM + c0);
            const float* wk;
#pragma unroll
            for (int e = 0; e < 8; e++) {
                wk = reinterpret_cast<const float*>(&wv[e]);
                a8[e] = fmaf((float)zv[e], wk[k], a8[e]);
            }
        }
    }
    bf16x8 o;
#pragma unroll
    for (int e = 0; e < 8; e++) o[e] = (bf16)(a8[e] / (1.f + expf(-a8[e])));
    *reinterpret_cast<bf16x8*>(x + (size_t)bl * DINNER + c0) = o;
}

// ---------------- la = log(a_bar) = -softplus(dt+dp)*|dt| ----------------
__global__ void la_kernel(const float* __restrict__ dt_in, const float* __restrict__ dparam,
                          float* __restrict__ la)
{
    int i = blockIdx.x * 256 + threadIdx.x;
    if (i >= BLROWS * NHEADS) return;
    int h = i & (NHEADS - 1);
    float dt = dt_in[i];
    float v = dt + dparam[h];
    float sp = (v > 20.f) ? v : log1pf(expf(v));
    la[i] = -sp * fabsf(dt);
}

// ================= chunked scan, SSD matmul form =================
__global__ __launch_bounds__(256) void chunk_state_kernel(
    const bf16* __restrict__ x,    // [BL][DINNER]
    const bf16* __restrict__ zb,   // B at col DINNER+h*64, stride ZDIM
    const float* __restrict__ la,  // [BL][16] log a
    bf16* __restrict__ S,          // [B][NCHUNK][NHEADS][128*64]
    float* __restrict__ Adec)      // [B][NHEADS][NCHUNK] = exp(Ls_Q)
{
    __shared__ __align__(16) bf16 xt[HEADDIM * QCHUNK]; // [d][t] swizzled
    __shared__ __align__(16) bf16 bw[DSTATE * QCHUNK];  // [s][t] swizzled, weighted
    __shared__ float Ls[QCHUNK];
    const int blk = blockIdx.x;
    const int h = blk & 15, c = (blk >> 4) & 63, b = blk >> 10;
    const int tid = threadIdx.x, lane = tid & 63, w = tid >> 6;
    const size_t row0 = (size_t)b * LSEQ + (size_t)c * QCHUNK;
    const bf16* xg = x + row0 * DINNER + h * HEADDIM;
    const bf16* Bg = zb + row0 * ZDIM + DINNER + h * DSTATE;

    const int t = tid >> 2, dseg = (tid & 3) * 32, sseg = (tid & 3) * 16;
    bf16x8 xr[4], br[2];
#pragma unroll
    for (int q = 0; q < 4; q++)
        xr[q] = *reinterpret_cast<const bf16x8*>(xg + (size_t)t * DINNER + dseg + q * 8);
#pragma unroll
    for (int q = 0; q < 2; q++)
        br[q] = *reinterpret_cast<const bf16x8*>(Bg + (size_t)t * ZDIM + sseg + q * 8);

    if (w == 0) {
        float v = la[(row0 + lane) * NHEADS + h];
#pragma unroll
        for (int off = 1; off < 64; off <<= 1) { float o = __shfl_up(v, off); if (lane >= off) v += o; }
        Ls[lane] = v;
        if (lane == 63) Adec[((size_t)b * NHEADS + h) * NCHUNK + c] = __expf(v);
    }
    __syncthreads();
    const float wt = __expf(Ls[QCHUNK - 1] - Ls[t]);
    const int tb = t >> 3, ti = t & 7;
#pragma unroll
    for (int q = 0; q < 4; q++)
#pragma unroll
        for (int j = 0; j < 8; j++) {
            int d = dseg + q * 8 + j;
            xt[d * 64 + ((tb ^ (d & 7)) << 3) + ti] = xr[q][j];
        }
#pragma unroll
    for (int q = 0; q < 2; q++)
#pragma unroll
        for (int j = 0; j < 8; j++) {
            int s = sseg + q * 8 + j;
            bw[s * 64 + ((tb ^ (s & 7)) << 3) + ti] = (bf16)((float)br[q][j] * wt);
        }
    __syncthreads();

    f32x4 acc[2][4];
#pragma unroll
    for (int i = 0; i < 2; i++)
#pragma unroll
        for (int j = 0; j < 4; j++) acc[i][j] = (f32x4){0.f, 0.f, 0.f, 0.f};
#pragma unroll
    for (int kk = 0; kk < 2; kk++) {
        const int kb = kk * 4 + (lane >> 4);
        bf16x8 af[2], bf2[4];
#pragma unroll
        for (int i = 0; i < 2; i++) {
            int d = w * 32 + i * 16 + (lane & 15);
            af[i] = *reinterpret_cast<const bf16x8*>(&xt[d * 64 + ((kb ^ (d & 7)) << 3)]);
        }
#pragma unroll
        for (int j = 0; j < 4; j++) {
            int s = j * 16 + (lane & 15);
            bf2[j] = *reinterpret_cast<const bf16x8*>(&bw[s * 64 + ((kb ^ (s & 7)) << 3)]);
        }
#pragma unroll
        for (int i = 0; i < 2; i++)
#pragma unroll
            for (int j = 0; j < 4; j++)
                acc[i][j] = __builtin_amdgcn_mfma_f32_16x16x32_bf16(af[i], bf2[j], acc[i][j], 0, 0, 0);
    }
    bf16* Sg = S + ((size_t)(b * NCHUNK + c) * NHEADS + h) * (HEADDIM * DSTATE);
    const int rr = (lane >> 4) * 4, ccol = lane & 15;
#pragma unroll
    for (int i = 0; i < 2; i++)
#pragma unroll
        for (int j = 0; j < 4; j++)
#pragma unroll
            for (int r = 0; r < 4; r++)
                Sg[(w * 32 + i * 16 + rr + r) * 64 + j * 16 + ccol] = (bf16)acc[i][j][r];
}

// Pass 1b: inter-chunk carry, in-place: S_c -> H_c (state at chunk START).
__global__ void chunk_carry_kernel(bf16* S, const float* __restrict__ A)
{
    int gid = blockIdx.x * 256 + threadIdx.x;
    if (gid >= BATCH * NHEADS * HEADDIM * DSTATE) return;
    int es = gid & (HEADDIM * DSTATE - 1);
    int h  = (gid >> 13) & (NHEADS - 1);
    int b  = gid >> 17;
    const float* Ab = A + ((size_t)b * NHEADS + h) * NCHUNK;
    float hstate = 0.f;
    size_t stride = (size_t)NHEADS * HEADDIM * DSTATE;
    bf16* p = S + ((size_t)b * NCHUNK * NHEADS + h) * (HEADDIM * DSTATE) + es;
    for (int c = 0; c < NCHUNK; ++c) {
        float sv = (float)*p;
        *p = (bf16)hstate;
        hstate = fmaf(Ab[c], hstate, sv);
        p += stride;
    }
}

// Pass 2: Y^T[d][t] = [Xt | H] @ [MG | P.C]^T  (K = 64 t' + 64 s), in-place over X.
__global__ __launch_bounds__(256) void chunk_y_kernel(
    bf16* xy,                       // [BL][DINNER]: x in, y out (same storage)
    const bf16* __restrict__ zb,    // B/C in z, stride ZDIM
    const float* __restrict__ la,   // [BL][16] log a
    const bf16* __restrict__ H)     // [B][NCHUNK][NHEADS][128*64] chunk-start state
{
    __shared__ __align__(16) bf16 bc[QCHUNK * 128];    // B | C, later MG[64][128]
    __shared__ __align__(16) bf16 xt[HEADDIM * QCHUNK];
    __shared__ __align__(16) bf16 hl[HEADDIM * DSTATE];
    __shared__ float Ls[QCHUNK];
    const int blk = blockIdx.x;
    const int h = blk & 15, c = (blk >> 4) & 63, b = blk >> 10;
    const int tid = threadIdx.x, lane = tid & 63, w = tid >> 6;
    const size_t row0 = (size_t)b * LSEQ + (size_t)c * QCHUNK;
    bf16* xg = xy + row0 * DINNER + h * HEADDIM;
    const bf16* Bg = zb + row0 * ZDIM + DINNER + h * DSTATE;
    const bf16* Cg = Bg + NHEADS * DSTATE;
    const bf16* Hg = H + ((size_t)(b * NCHUNK + c) * NHEADS + h) * (HEADDIM * DSTATE);

#pragma unroll
    for (int it = 0; it < 2; it++) {
        int idx = it * 256 + tid;
        int row = idx >> 3, p = idx & 7;
        int sc = (p ^ (row & 7)) << 3;
        __builtin_amdgcn_global_load_lds((const AS1 void*)(Bg + (size_t)row * ZDIM + sc),
                                         (AS3 void*)(&bc[idx * 8]), 16, 0, 0);
        __builtin_amdgcn_global_load_lds((const AS1 void*)(Cg + (size_t)row * ZDIM + sc),
                                         (AS3 void*)(&bc[4096 + idx * 8]), 16, 0, 0);
    }
#pragma unroll
    for (int it = 0; it < 4; it++) {
        int idx = it * 256 + tid;
        int d = idx >> 3, p = idx & 7;
        __builtin_amdgcn_global_load_lds((const AS1 void*)(Hg + d * 64 + ((p ^ (d & 7)) << 3)),
                                         (AS3 void*)(&hl[idx * 8]), 16, 0, 0);
    }
    const int t = tid >> 2, dseg = (tid & 3) * 32, sseg = (tid & 3) * 16;
    bf16x8 xr[4];
#pragma unroll
    for (int q = 0; q < 4; q++)
        xr[q] = *reinterpret_cast<const bf16x8*>(xg + (size_t)t * DINNER + dseg + q * 8);
    if (w == 0) {
        float v = la[(row0 + lane) * NHEADS + h];
#pragma unroll
        for (int off = 1; off < 64; off <<= 1) { float o = __shfl_up(v, off); if (lane >= off) v += o; }
        Ls[lane] = v;
    }
    __syncthreads();

    const int tb = t >> 3, ti = t & 7;
#pragma unroll
    for (int q = 0; q < 4; q++)
#pragma unroll
        for (int j = 0; j < 8; j++) {
            int d = dseg + q * 8 + j;
            xt[d * 64 + ((tb ^ (d & 7)) << 3) + ti] = xr[q][j];
        }

    f32x4 g[4];
#pragma unroll
    for (int j = 0; j < 4; j++) g[j] = (f32x4){0.f, 0.f, 0.f, 0.f};
#pragma unroll
    for (int kk = 0; kk < 2; kk++) {
        const int kb = kk * 4 + (lane >> 4);
        const int tA = w * 16 + (lane & 15);
        bf16x8 ca = *reinterpret_cast<const bf16x8*>(&bc[4096 + tA * 64 + ((kb ^ (tA & 7)) << 3)]);
#pragma unroll
        for (int j = 0; j < 4; j++) {
            int tB = j * 16 + (lane & 15);
            bf16x8 bb = *reinterpret_cast<const bf16x8*>(&bc[tB * 64 + ((kb ^ (tB & 7)) << 3)]);
            g[j] = __builtin_amdgcn_mfma_f32_16x16x32_bf16(ca, bb, g[j], 0, 0, 0);
        }
    }
    bf16x8 cr[2];
#pragma unroll
    for (int q = 0; q < 2; q++) {
        int sblk = (sseg >> 3) + q;
        cr[q] = *reinterpret_cast<const bf16x8*>(&bc[4096 + t * 64 + ((sblk ^ (t & 7)) << 3)]);
    }
    const float pscale = __expf(Ls[t]);
    __syncthreads();

    {
        const int tpbase = lane & 15;
        const int tgbase = w * 16 + (lane >> 4) * 4;
        float lst[4];
#pragma unroll
        for (int r = 0; r < 4; r++) lst[r] = Ls[tgbase + r];
#pragma unroll
        for (int j = 0; j < 4; j++) {
            int tp = j * 16 + tpbase;
            float lstp = Ls[tp];
#pragma unroll
            for (int r = 0; r < 4; r++) {
                int tg = tgbase + r;
                float mg = (tp <= tg) ? g[j][r] * __expf(lst[r] - lstp) : 0.f;
                bc[tg * 128 + (((tp >> 3) ^ (tg & 7)) << 3) + (tp & 7)] = (bf16)mg;
            }
        }
    }
#pragma unroll
    for (int q = 0; q < 2; q++) {
        int sblk = (sseg >> 3) + q;
        bf16x8 o;
#pragma unroll
        for (int j = 0; j < 8; j++) o[j] = (bf16)((float)cr[q][j] * pscale);
        *reinterpret_cast<bf16x8*>(&bc[t * 128 + ((8 + (sblk ^ (t & 7))) << 3)]) = o;
    }
    __syncthreads();

    f32x4 acc[2][4];
#pragma unroll
    for (int i = 0; i < 2; i++)
#pragma unroll
        for (int j = 0; j < 4; j++) acc[i][j] = (f32x4){0.f, 0.f, 0.f, 0.f};
#pragma unroll
    for (int kk = 0; kk < 4; kk++) {
        const int kb = kk * 4 + (lane >> 4);
        bf16x8 af[2];
#pragma unroll
        for (int i = 0; i < 2; i++) {
            int d = w * 32 + i * 16 + (lane & 15);
            if (kk < 2)
                af[i] = *reinterpret_cast<const bf16x8*>(&xt[d * 64 + ((kb ^ (d & 7)) << 3)]);
            else
                af[i] = *reinterpret_cast<const bf16x8*>(&hl[d * 64 + (((kb - 8) ^ (d & 7)) << 3)]);
        }
#pragma unroll
        for (int j = 0; j < 4; j++) {
            int tt = j * 16 + (lane & 15);
            bf16x8 b2 = *reinterpret_cast<const bf16x8*>(&bc[tt * 128 + ((kb ^ (tt & 7)) << 3)]);
#pragma unroll
            for (int i = 0; i < 2; i++)
                acc[i][j] = __builtin_amdgcn_mfma_f32_16x16x32_bf16(af[i], b2, acc[i][j], 0, 0, 0);
        }
    }
#pragma unroll
    for (int i = 0; i < 2; i++)
#pragma unroll
        for (int j = 0; j < 4; j++) {
            int d0 = w * 32 + i * 16 + (lane >> 4) * 4;
            int tt = j * 16 + (lane & 15);
            bf16x4 o;
#pragma unroll
            for (int r = 0; r < 4; r++) o[r] = (bf16)acc[i][j][r];
            *reinterpret_cast<bf16x4*>(xg + (size_t)tt * DINNER + d0) = o;
        }
}

// ---------------- gate (sigmoid) * y, RMS norm, -> bf16 (in-place over g, stride GPAD) ----
__global__ __launch_bounds__(256) void gate_rms_kernel(
    const bf16* __restrict__ y,   // [BL][2048]
    bf16* g,                      // [BL][GPAD]: gate pre-act in, normalized y out
    const float* __restrict__ norm_w)
{
    __shared__ float red[4];
    int row = blockIdx.x, t = threadIdx.x;
    const bf16* yr = y + (size_t)row * DINNER;
    bf16* gr = g + (size_t)row * GPAD;
    int c0 = t * 8;
    bf16x8 yv8 = *reinterpret_cast<const bf16x8*>(yr + c0);
    bf16x8 gv8 = *reinterpret_cast<const bf16x8*>(gr + c0);
    float v[8];
#pragma unroll
    for (int i = 0; i < 8; i++) {
        float yf = (float)yv8[i];
        float gf = (float)gv8[i];
        v[i] = yf / (1.f + expf(-gf));
    }
    float ss = 0.f;
#pragma unroll
    for (int i = 0; i < 8; i++) ss += v[i] * v[i];
#pragma unroll
    for (int off = 32; off >= 1; off >>= 1) ss += __shfl_xor(ss, off);
    if ((t & 63) == 0) red[t >> 6] = ss;
    __syncthreads();
    ss = red[0] + red[1] + red[2] + red[3];
    float sc = rsqrtf(ss * (1.0f / DINNER) + 1.1920928955078125e-07f);
    float4 na = *reinterpret_cast<const float4*>(norm_w + c0);
    float4 nb = *reinterpret_cast<const float4*>(norm_w + c0 + 4);
    bf16x8 ov;
    ov[0] = (bf16)(v[0] * sc * na.x);
    ov[1] = (bf16)(v[1] * sc * na.y);
    ov[2] = (bf16)(v[2] * sc * na.z);
    ov[3] = (bf16)(v[3] * sc * na.w);
    ov[4] = (bf16)(v[4] * sc * nb.x);
    ov[5] = (bf16)(v[5] * sc * nb.y);
    ov[6] = (bf16)(v[6] * sc * nb.z);
    ov[7] = (bf16)(v[7] * sc * nb.w);
    *reinterpret_cast<bf16x8*>(gr + c0) = ov;
}

// ---------------- launch ----------------
extern "C" void kernel_launch(void* const* d_in, const int* in_sizes, int n_in,
                              void* d_out, int out_size, void* d_ws, size_t ws_size,
                              hipStream_t stream)
{
    const float* u      = (const float*)d_in[0];
    const float* W_in   = (const float*)d_in[1];
    const float* conv_w = (const float*)d_in[2];
    const float* conv_b = (const float*)d_in[3];
    const float* dparam = (const float*)d_in[4];
    const float* W_gate = (const float*)d_in[5];
    const float* norm_w = (const float*)d_in[6];
    const float* W_out  = (const float*)d_in[7];
    float* out = (float*)d_out;

    char* ws = (char*)d_ws;
    size_t off = 0;
    auto alloc = [&](size_t bytes) {
        void* p = ws + off;
        off += (bytes + 255) & ~(size_t)255;
        return p;
    };
    // total ws use: ~173 MB (padded strides)
    bf16*  u_bf  = (bf16*) alloc((size_t)BLROWS * UPAD * 2);     // 17.8 MB
    bf16*  Wt_f  = (bf16*) alloc((size_t)6400 * UPAD * 2);       // 13.9 MB (W_in | pad | W_gate | pad)
    bf16*  Wt_o  = (bf16*) alloc((size_t)DMODEL * GPAD * 2);     // 4.3 MB
    bf16*  z     = (bf16*) alloc((size_t)BLROWS * ZDIM * 2);     // 67.4 MB
    bf16*  g     = (bf16*) alloc((size_t)BLROWS * GPAD * 2);     // 34.6 MB (yn in-place)
    float* dt    = (float*)alloc((size_t)BLROWS * NHEADS * 4);   // 0.5 MB
    float* lab   = (float*)alloc((size_t)BLROWS * NHEADS * 4);   // 0.5 MB (log a)
    bf16*  S     = (bf16*) alloc((size_t)BATCH * NCHUNK * NHEADS * HEADDIM * DSTATE * 2); // 33.6 MB
    float* Adec  = (float*)alloc((size_t)BATCH * NHEADS * NCHUNK * 4);                    // 8 KB
    bf16* xy = (bf16*)d_out;   // x/y live in d_out, fully overwritten by final GEMM
    (void)ws_size; (void)in_sizes; (void)n_in; (void)out_size;

    dim3 tb(32, 8);
    cvt_pad_kernel<<<BLROWS, 256, 0, stream>>>(u, u_bf);
    // fused weight: rows 0..4111 = W_in^T, 4112..4223 = 0, 4224..6271 = W_gate^T, 6272..6399 = 0
    transpose_cvt_kernel<<<dim3(4224 / 32, DMODEL / 32), tb, 0, stream>>>(W_in, Wt_f, DMODEL, ZDIM, 4224, UPAD);
    transpose_cvt_kernel<<<dim3(2176 / 32, DMODEL / 32), tb, 0, stream>>>(W_gate, Wt_f + (size_t)4224 * UPAD, DMODEL, DINNER, 2176, UPAD);
    transpose_cvt_kernel<<<dim3(DMODEL / 32, DINNER / 32), tb, 0, stream>>>(W_out, Wt_o, DINNER, DMODEL, DMODEL, GPAD);

    // fused z|g GEMM: M=8192 (32 bm of 256), K=1024 @stride1088 (32 slices), N=6400 (50 bn of 128)
    gemm_w128_kernel<32, UPAD, 50><<<32 * 50, 256, 0, stream>>>(
        u_bf, Wt_f, z, g, dt);

    conv_silu_kernel<<<(BLROWS * (DINNER / 8) + 255) / 256, 256, 0, stream>>>(z, conv_w, conv_b, xy);
    la_kernel<<<(BLROWS * NHEADS + 255) / 256, 256, 0, stream>>>(dt, dparam, lab);

    // chunked scan (SSD matmul form)
    chunk_state_kernel<<<BATCH * NCHUNK * NHEADS, 256, 0, stream>>>(xy, z, lab, S, Adec);
    chunk_carry_kernel<<<(BATCH * NHEADS * HEADDIM * DSTATE) / 256, 256, 0, stream>>>(S, Adec);
    chunk_y_kernel<<<BATCH * NCHUNK * NHEADS, 256, 0, stream>>>(xy, z, lab, S);

    gate_rms_kernel<<<BLROWS, 256, 0, stream>>>(xy, g, norm_w);

    // out = yn @ W_out (f32 out): M=8192 (64 bm), K=2048 @stride2112 (64 slices), N=1024 (8 bn)
    gemm_db_kernel<64, GPAD, 8><<<64 * 8, 256, 0, stream>>>(g, Wt_o, out);
}

// Round 15
// 359.920 us; speedup vs baseline: 1.1002x; 1.1002x over previous
//
#include <hip/hip_runtime.h>

#define BATCH   2
#define LSEQ    4096
#define DMODEL  1024
#define DINNER  2048
#define NHEADS  16
#define DSTATE  64
#define HEADDIM 128
#define ZDIM    4112
#define BLROWS  (BATCH*LSEQ)   // 8192
#define QCHUNK  64
#define NCHUNK  (LSEQ/QCHUNK)  // 64
#define UPAD    1088           // padded K-stride for u_bf / Wt_f rows
#define GPAD    2112           // padded K-stride for yn(g) / Wt_o rows

#define AS1 __attribute__((address_space(1)))
#define AS3 __attribute__((address_space(3)))

typedef __bf16 bf16;
typedef __bf16 bf16x8 __attribute__((ext_vector_type(8)));
typedef __bf16 bf16x4 __attribute__((ext_vector_type(4)));
typedef float  f32x4  __attribute__((ext_vector_type(4)));

// paired-row LDS swizzle for [R rows][32 bf16] regions (verified conflict-free rounds 8-14)
__device__ __forceinline__ int lds_elem(int row, int c)
{
    return (row >> 1) * 64 + (row & 1) * 32 + (((c ^ ((row >> 1) & 3)) & 3) << 3);
}

// ---------------- fp32 -> bf16 convert with padded row stride ----------------
__global__ void cvt_pad_kernel(const float* __restrict__ in, bf16* __restrict__ out)
{
    int gid = blockIdx.x * 256 + threadIdx.x;   // 8192 rows x 256 quads
    int row = gid >> 8, c4 = (gid & 255) * 4;
    float4 v = *reinterpret_cast<const float4*>(in + (size_t)row * DMODEL + c4);
    bf16x4 o;
    o[0] = (bf16)v.x; o[1] = (bf16)v.y; o[2] = (bf16)v.z; o[3] = (bf16)v.w;
    *reinterpret_cast<bf16x4*>(out + (size_t)row * UPAD + c4) = o;
}

// ---------------- transpose + convert: src[R][C] f32 -> dst[Cpad rows][stride dstS] bf16 ----
__global__ void transpose_cvt_kernel(const float* __restrict__ src, bf16* __restrict__ dst,
                                     int R, int C, int Cpad, int dstS)
{
    __shared__ float tile[32][33];
    int tx = threadIdx.x;   // 0..31
    int ty = threadIdx.y;   // 0..7
    int c0 = blockIdx.x * 32;
    int r0 = blockIdx.y * 32;
#pragma unroll
    for (int q = 0; q < 4; q++) {
        int r = r0 + ty + q * 8;
        int c = c0 + tx;
        float v = 0.f;
        if (r < R && c < C) v = src[(size_t)r * C + c];
        tile[ty + q * 8][tx] = v;
    }
    __syncthreads();
#pragma unroll
    for (int q = 0; q < 4; q++) {
        int oc = c0 + ty + q * 8;   // output row (= original col)
        int orr = r0 + tx;          // output col (= original row)
        if (oc < Cpad && orr < R)
            dst[(size_t)oc * dstS + orr] = (bf16)tile[tx][ty + q * 8];
    }
}

// ======= triple-buffered dbuf GEMM: 128x128, 4 waves, BK=32, 3 LDS slots (48KB) =======
// Pipeline depth 2 phases: during phase p, STAGE(p+3) into the just-freed slot; end-of-phase
// vmcnt(8) certifies slot p+1 (issued two phases earlier, ~1700 cyc slack > load latency).
// No setprio (m190: hurts lockstep GEMM / starves co-resident blocks' staging waves).
// MODE 0: fused z|g epilogue + inline la(dt).  MODE 1: f32 C[M][1024].
template<int NSLICE, int KROW, int MODE, int NBN>
__global__ __launch_bounds__(256) void gemm_db3_kernel(
    const bf16* __restrict__ A, const bf16* __restrict__ Bt,
    bf16* __restrict__ z, bf16* __restrict__ g, float* __restrict__ lab,
    const float* __restrict__ dparam, float* __restrict__ c32)
{
    constexpr int SLOTSZ = 256 * 32;                 // 8192 bf16 = 16 KB
    __shared__ __align__(16) bf16 lds[3 * SLOTSZ];   // 48 KB
    const int tid = threadIdx.x;
    const int lane = tid & 63, wid = tid >> 6;
    const int wm = (wid >> 1) * 64, wn = (wid & 1) * 64;
    const int lml = lane & 15, kc = lane >> 4;

    const int bid = blockIdx.x;
    const int xcd = bid & 7;
    const int idx = bid >> 3;
    const int bm = xcd * 8 + (idx & 7);
    const int bn = idx >> 3;

    const bf16* Abase = A + (size_t)(bm * 128) * KROW;
    const bf16* Bbase = Bt + (size_t)(bn * 128) * KROW;

#define STAGE8(pp) do {                                                                  \
    const int _p = (pp); const int _slot = _p % 3; const size_t _ko = (size_t)_p * 32;   \
    _Pragma("unroll") for (int it = 0; it < 4; ++it) {                                   \
        int q = it * 256 + tid;                                                          \
        int o = (q < 512) ? q : q - 512;                                                 \
        int prow = o >> 3, wi = o & 7;                                                   \
        int row = prow * 2 + (wi >> 2), c = (wi & 3) ^ (prow & 3);                       \
        const bf16* _src = ((q < 512) ? Abase : Bbase) + (size_t)row * KROW + _ko + c * 8; \
        int _dst = _slot * SLOTSZ + ((q < 512) ? 0 : 4096) + o * 8;                      \
        __builtin_amdgcn_global_load_lds((const AS1 void*)_src,                          \
            (AS3 void*)(&lds[_dst]), 16, 0, 0);                                          \
    }                                                                                    \
} while (0)

    f32x4 acc[4][4];
#pragma unroll
    for (int i = 0; i < 4; i++)
#pragma unroll
        for (int j = 0; j < 4; j++) acc[i][j] = (f32x4){0.f, 0.f, 0.f, 0.f};

    STAGE8(0); STAGE8(1); STAGE8(2);
    asm volatile("s_waitcnt vmcnt(8)" ::: "memory");   // slot 0 landed (1,2 in flight)
    __builtin_amdgcn_s_barrier();

    for (int p = 0; p < NSLICE; ++p) {
        const bf16* base_ = &lds[(p % 3) * SLOTSZ];
        bf16x8 af[4], bfv[4];
#pragma unroll
        for (int i = 0; i < 4; ++i) {
            int row = wm + i * 16 + lml;
            af[i] = *reinterpret_cast<const bf16x8*>(&base_[lds_elem(row, kc)]);
        }
#pragma unroll
        for (int j = 0; j < 4; ++j) {
            int row = wn + j * 16 + lml;
            bfv[j] = *reinterpret_cast<const bf16x8*>(&base_[4096 + lds_elem(row, kc)]);
        }
        asm volatile("s_waitcnt lgkmcnt(0)" ::: "memory");
        __builtin_amdgcn_sched_barrier(0);
        __builtin_amdgcn_s_barrier();        // slot p fully consumed by all waves
        if (p + 3 < NSLICE) STAGE8(p + 3);   // refill the just-freed slot
#pragma unroll
        for (int i = 0; i < 4; ++i)
#pragma unroll
            for (int j = 0; j < 4; ++j)
                acc[i][j] = __builtin_amdgcn_mfma_f32_16x16x32_bf16(af[i], bfv[j], acc[i][j], 0, 0, 0);
        if (p + 1 < NSLICE) {
            if (p + 3 < NSLICE)       { asm volatile("s_waitcnt vmcnt(8)" ::: "memory"); }
            else if (p + 2 < NSLICE)  { asm volatile("s_waitcnt vmcnt(4)" ::: "memory"); }
            else                      { asm volatile("s_waitcnt vmcnt(0)" ::: "memory"); }
            __builtin_amdgcn_s_barrier();
        }
    }
#undef STAGE8

    const int rbase = (lane >> 4) * 4;
#pragma unroll
    for (int i = 0; i < 4; i++) {
#pragma unroll
        for (int j = 0; j < 4; j++) {
            int col = bn * 128 + wn + j * 16 + lml;
            if constexpr (MODE == 0) {
                bool isZ = (col < ZDIM);
                bool isG = (col >= 4224) && (col < 4224 + DINNER);
                bool isDT = (col >= 4096) && (col < ZDIM);
                if (!isZ && !isG) continue;
#pragma unroll
                for (int r = 0; r < 4; r++) {
                    int row = bm * 128 + wm + i * 16 + rbase + r;
                    float v = acc[i][j][r];
                    if (isZ) {
                        z[(size_t)row * ZDIM + col] = (bf16)v;
                        if (isDT) {
                            int h = col - 4096;
                            float v2 = v + dparam[h];
                            float sp = (v2 > 20.f) ? v2 : log1pf(expf(v2));
                            lab[(size_t)row * NHEADS + h] = -sp * fabsf(v);
                        }
                    } else {
                        g[(size_t)row * GPAD + (col - 4224)] = (bf16)v;
                    }
                }
            } else {
#pragma unroll
                for (int r = 0; r < 4; r++) {
                    int row = bm * 128 + wm + i * 16 + rbase + r;
                    c32[(size_t)row * 1024 + col] = acc[i][j][r];
                }
            }
        }
    }
}

// ---------------- causal depthwise conv (D_CONV=4) + SiLU, bf16x8 vectorized ----------------
__global__ void conv_silu_kernel(const bf16* __restrict__ z, const float* __restrict__ conv_w,
                                 const float* __restrict__ conv_b, bf16* __restrict__ x)
{
    int gid = blockIdx.x * 256 + threadIdx.x;   // one thread per 8 channels
    if (gid >= BLROWS * (DINNER / 8)) return;
    int c0 = (gid & 255) * 8;
    int bl = gid >> 8;
    int l = bl & (LSEQ - 1);
    float4 wv[8];
#pragma unroll
    for (int e = 0; e < 8; e++) wv[e] = *reinterpret_cast<const float4*>(conv_w + (size_t)(c0 + e) * 4);
    float a8[8];
    {
        float4 b0 = *reinterpret_cast<const float4*>(conv_b + c0);
        float4 b1 = *reinterpret_cast<const float4*>(conv_b + c0 + 4);
        a8[0] = b0.x; a8[1] = b0.y; a8[2] = b0.z; a8[3] = b0.w;
        a8[4] = b1.x; a8[5] = b1.y; a8[6] = b1.z; a8[7] = b1.w;
    }
#pragma unroll
    for (int k = 0; k < 4; k++) {
        if (l - 3 + k >= 0) {
            bf16x8 zv = *reinterpret_cast<const bf16x8*>(z + (size_t)(bl - 3 + k) * ZDIM + c0);
            const float* wk;
#pragma unroll
            for (int e = 0; e < 8; e++) {
                wk = reinterpret_cast<const float*>(&wv[e]);
                a8[e] = fmaf((float)zv[e], wk[k], a8[e]);
            }
        }
    }
    bf16x8 o;
#pragma unroll
    for (int e = 0; e < 8; e++) o[e] = (bf16)(a8[e] / (1.f + expf(-a8[e])));
    *reinterpret_cast<bf16x8*>(x + (size_t)bl * DINNER + c0) = o;
}

// ================= chunked scan, SSD matmul form =================
__global__ __launch_bounds__(256) void chunk_state_kernel(
    const bf16* __restrict__ x,    // [BL][DINNER]
    const bf16* __restrict__ zb,   // B at col DINNER+h*64, stride ZDIM
    const float* __restrict__ la,  // [BL][16] log a
    bf16* __restrict__ S,          // [B][NCHUNK][NHEADS][128*64]
    float* __restrict__ Adec)      // [B][NHEADS][NCHUNK] = exp(Ls_Q)
{
    __shared__ __align__(16) bf16 xt[HEADDIM * QCHUNK]; // [d][t] swizzled
    __shared__ __align__(16) bf16 bw[DSTATE * QCHUNK];  // [s][t] swizzled, weighted
    __shared__ float Ls[QCHUNK];
    const int blk = blockIdx.x;
    const int h = blk & 15, c = (blk >> 4) & 63, b = blk >> 10;
    const int tid = threadIdx.x, lane = tid & 63, w = tid >> 6;
    const size_t row0 = (size_t)b * LSEQ + (size_t)c * QCHUNK;
    const bf16* xg = x + row0 * DINNER + h * HEADDIM;
    const bf16* Bg = zb + row0 * ZDIM + DINNER + h * DSTATE;

    const int t = tid >> 2, dseg = (tid & 3) * 32, sseg = (tid & 3) * 16;
    bf16x8 xr[4], br[2];
#pragma unroll
    for (int q = 0; q < 4; q++)
        xr[q] = *reinterpret_cast<const bf16x8*>(xg + (size_t)t * DINNER + dseg + q * 8);
#pragma unroll
    for (int q = 0; q < 2; q++)
        br[q] = *reinterpret_cast<const bf16x8*>(Bg + (size_t)t * ZDIM + sseg + q * 8);

    if (w == 0) {
        float v = la[(row0 + lane) * NHEADS + h];
#pragma unroll
        for (int off = 1; off < 64; off <<= 1) { float o = __shfl_up(v, off); if (lane >= off) v += o; }
        Ls[lane] = v;
        if (lane == 63) Adec[((size_t)b * NHEADS + h) * NCHUNK + c] = __expf(v);
    }
    __syncthreads();
    const float wt = __expf(Ls[QCHUNK - 1] - Ls[t]);
    const int tb = t >> 3, ti = t & 7;
#pragma unroll
    for (int q = 0; q < 4; q++)
#pragma unroll
        for (int j = 0; j < 8; j++) {
            int d = dseg + q * 8 + j;
            xt[d * 64 + ((tb ^ (d & 7)) << 3) + ti] = xr[q][j];
        }
#pragma unroll
    for (int q = 0; q < 2; q++)
#pragma unroll
        for (int j = 0; j < 8; j++) {
            int s = sseg + q * 8 + j;
            bw[s * 64 + ((tb ^ (s & 7)) << 3) + ti] = (bf16)((float)br[q][j] * wt);
        }
    __syncthreads();

    f32x4 acc[2][4];
#pragma unroll
    for (int i = 0; i < 2; i++)
#pragma unroll
        for (int j = 0; j < 4; j++) acc[i][j] = (f32x4){0.f, 0.f, 0.f, 0.f};
#pragma unroll
    for (int kk = 0; kk < 2; kk++) {
        const int kb = kk * 4 + (lane >> 4);
        bf16x8 af[2], bf2[4];
#pragma unroll
        for (int i = 0; i < 2; i++) {
            int d = w * 32 + i * 16 + (lane & 15);
            af[i] = *reinterpret_cast<const bf16x8*>(&xt[d * 64 + ((kb ^ (d & 7)) << 3)]);
        }
#pragma unroll
        for (int j = 0; j < 4; j++) {
            int s = j * 16 + (lane & 15);
            bf2[j] = *reinterpret_cast<const bf16x8*>(&bw[s * 64 + ((kb ^ (s & 7)) << 3)]);
        }
#pragma unroll
        for (int i = 0; i < 2; i++)
#pragma unroll
            for (int j = 0; j < 4; j++)
                acc[i][j] = __builtin_amdgcn_mfma_f32_16x16x32_bf16(af[i], bf2[j], acc[i][j], 0, 0, 0);
    }
    bf16* Sg = S + ((size_t)(b * NCHUNK + c) * NHEADS + h) * (HEADDIM * DSTATE);
    const int rr = (lane >> 4) * 4, ccol = lane & 15;
#pragma unroll
    for (int i = 0; i < 2; i++)
#pragma unroll
        for (int j = 0; j < 4; j++)
#pragma unroll
            for (int r = 0; r < 4; r++)
                Sg[(w * 32 + i * 16 + rr + r) * 64 + j * 16 + ccol] = (bf16)acc[i][j][r];
}

// Pass 1b: inter-chunk carry, in-place: S_c -> H_c (state at chunk START).
__global__ void chunk_carry_kernel(bf16* S, const float* __restrict__ A)
{
    int gid = blockIdx.x * 256 + threadIdx.x;
    if (gid >= BATCH * NHEADS * HEADDIM * DSTATE) return;
    int es = gid & (HEADDIM * DSTATE - 1);
    int h  = (gid >> 13) & (NHEADS - 1);
    int b  = gid >> 17;
    const float* Ab = A + ((size_t)b * NHEADS + h) * NCHUNK;
    float hstate = 0.f;
    size_t stride = (size_t)NHEADS * HEADDIM * DSTATE;
    bf16* p = S + ((size_t)b * NCHUNK * NHEADS + h) * (HEADDIM * DSTATE) + es;
    for (int c = 0; c < NCHUNK; ++c) {
        float sv = (float)*p;
        *p = (bf16)hstate;
        hstate = fmaf(Ab[c], hstate, sv);
        p += stride;
    }
}

// Pass 2: Y^T[d][t] = [Xt | H] @ [MG | P.C]^T  (K = 64 t' + 64 s), in-place over X.
__global__ __launch_bounds__(256) void chunk_y_kernel(
    bf16* xy,                       // [BL][DINNER]: x in, y out (same storage)
    const bf16* __restrict__ zb,    // B/C in z, stride ZDIM
    const float* __restrict__ la,   // [BL][16] log a
    const bf16* __restrict__ H)     // [B][NCHUNK][NHEADS][128*64] chunk-start state
{
    __shared__ __align__(16) bf16 bc[QCHUNK * 128];    // B | C, later MG[64][128]
    __shared__ __align__(16) bf16 xt[HEADDIM * QCHUNK];
    __shared__ __align__(16) bf16 hl[HEADDIM * DSTATE];
    __shared__ float Ls[QCHUNK];
    const int blk = blockIdx.x;
    const int h = blk & 15, c = (blk >> 4) & 63, b = blk >> 10;
    const int tid = threadIdx.x, lane = tid & 63, w = tid >> 6;
    const size_t row0 = (size_t)b * LSEQ + (size_t)c * QCHUNK;
    bf16* xg = xy + row0 * DINNER + h * HEADDIM;
    const bf16* Bg = zb + row0 * ZDIM + DINNER + h * DSTATE;
    const bf16* Cg = Bg + NHEADS * DSTATE;
    const bf16* Hg = H + ((size_t)(b * NCHUNK + c) * NHEADS + h) * (HEADDIM * DSTATE);

#pragma unroll
    for (int it = 0; it < 2; it++) {
        int idx = it * 256 + tid;
        int row = idx >> 3, p = idx & 7;
        int sc = (p ^ (row & 7)) << 3;
        __builtin_amdgcn_global_load_lds((const AS1 void*)(Bg + (size_t)row * ZDIM + sc),
                                         (AS3 void*)(&bc[idx * 8]), 16, 0, 0);
        __builtin_amdgcn_global_load_lds((const AS1 void*)(Cg + (size_t)row * ZDIM + sc),
                                         (AS3 void*)(&bc[4096 + idx * 8]), 16, 0, 0);
    }
#pragma unroll
    for (int it = 0; it < 4; it++) {
        int idx = it * 256 + tid;
        int d = idx >> 3, p = idx & 7;
        __builtin_amdgcn_global_load_lds((const AS1 void*)(Hg + d * 64 + ((p ^ (d & 7)) << 3)),
                                         (AS3 void*)(&hl[idx * 8]), 16, 0, 0);
    }
    const int t = tid >> 2, dseg = (tid & 3) * 32, sseg = (tid & 3) * 16;
    bf16x8 xr[4];
#pragma unroll
    for (int q = 0; q < 4; q++)
        xr[q] = *reinterpret_cast<const bf16x8*>(xg + (size_t)t * DINNER + dseg + q * 8);
    if (w == 0) {
        float v = la[(row0 + lane) * NHEADS + h];
#pragma unroll
        for (int off = 1; off < 64; off <<= 1) { float o = __shfl_up(v, off); if (lane >= off) v += o; }
        Ls[lane] = v;
    }
    __syncthreads();

    const int tb = t >> 3, ti = t & 7;
#pragma unroll
    for (int q = 0; q < 4; q++)
#pragma unroll
        for (int j = 0; j < 8; j++) {
            int d = dseg + q * 8 + j;
            xt[d * 64 + ((tb ^ (d & 7)) << 3) + ti] = xr[q][j];
        }

    f32x4 g[4];
#pragma unroll
    for (int j = 0; j < 4; j++) g[j] = (f32x4){0.f, 0.f, 0.f, 0.f};
#pragma unroll
    for (int kk = 0; kk < 2; kk++) {
        const int kb = kk * 4 + (lane >> 4);
        const int tA = w * 16 + (lane & 15);
        bf16x8 ca = *reinterpret_cast<const bf16x8*>(&bc[4096 + tA * 64 + ((kb ^ (tA & 7)) << 3)]);
#pragma unroll
        for (int j = 0; j < 4; j++) {
            int tB = j * 16 + (lane & 15);
            bf16x8 bb = *reinterpret_cast<const bf16x8*>(&bc[tB * 64 + ((kb ^ (tB & 7)) << 3)]);
            g[j] = __builtin_amdgcn_mfma_f32_16x16x32_bf16(ca, bb, g[j], 0, 0, 0);
        }
    }
    bf16x8 cr[2];
#pragma unroll
    for (int q = 0; q < 2; q++) {
        int sblk = (sseg >> 3) + q;
        cr[q] = *reinterpret_cast<const bf16x8*>(&bc[4096 + t * 64 + ((sblk ^ (t & 7)) << 3)]);
    }
    const float pscale = __expf(Ls[t]);
    __syncthreads();

    {
        const int tpbase = lane & 15;
        const int tgbase = w * 16 + (lane >> 4) * 4;
        float lst[4];
#pragma unroll
        for (int r = 0; r < 4; r++) lst[r] = Ls[tgbase + r];
#pragma unroll
        for (int j = 0; j < 4; j++) {
            int tp = j * 16 + tpbase;
            float lstp = Ls[tp];
#pragma unroll
            for (int r = 0; r < 4; r++) {
                int tg = tgbase + r;
                float mg = (tp <= tg) ? g[j][r] * __expf(lst[r] - lstp) : 0.f;
                bc[tg * 128 + (((tp >> 3) ^ (tg & 7)) << 3) + (tp & 7)] = (bf16)mg;
            }
        }
    }
#pragma unroll
    for (int q = 0; q < 2; q++) {
        int sblk = (sseg >> 3) + q;
        bf16x8 o;
#pragma unroll
        for (int j = 0; j < 8; j++) o[j] = (bf16)((float)cr[q][j] * pscale);
        *reinterpret_cast<bf16x8*>(&bc[t * 128 + ((8 + (sblk ^ (t & 7))) << 3)]) = o;
    }
    __syncthreads();

    f32x4 acc[2][4];
#pragma unroll
    for (int i = 0; i < 2; i++)
#pragma unroll
        for (int j = 0; j < 4; j++) acc[i][j] = (f32x4){0.f, 0.f, 0.f, 0.f};
#pragma unroll
    for (int kk = 0; kk < 4; kk++) {
        const int kb = kk * 4 + (lane >> 4);
        bf16x8 af[2];
#pragma unroll
        for (int i = 0; i < 2; i++) {
            int d = w * 32 + i * 16 + (lane & 15);
            if (kk < 2)
                af[i] = *reinterpret_cast<const bf16x8*>(&xt[d * 64 + ((kb ^ (d & 7)) << 3)]);
            else
                af[i] = *reinterpret_cast<const bf16x8*>(&hl[d * 64 + (((kb - 8) ^ (d & 7)) << 3)]);
        }
#pragma unroll
        for (int j = 0; j < 4; j++) {
            int tt = j * 16 + (lane & 15);
            bf16x8 b2 = *reinterpret_cast<const bf16x8*>(&bc[tt * 128 + ((kb ^ (tt & 7)) << 3)]);
#pragma unroll
            for (int i = 0; i < 2; i++)
                acc[i][j] = __builtin_amdgcn_mfma_f32_16x16x32_bf16(af[i], b2, acc[i][j], 0, 0, 0);
        }
    }
#pragma unroll
    for (int i = 0; i < 2; i++)
#pragma unroll
        for (int j = 0; j < 4; j++) {
            int d0 = w * 32 + i * 16 + (lane >> 4) * 4;
            int tt = j * 16 + (lane & 15);
            bf16x4 o;
#pragma unroll
            for (int r = 0; r < 4; r++) o[r] = (bf16)acc[i][j][r];
            *reinterpret_cast<bf16x4*>(xg + (size_t)tt * DINNER + d0) = o;
        }
}

// ---------------- gate (sigmoid) * y, RMS norm, -> bf16 (in-place over g, stride GPAD) ----
__global__ __launch_bounds__(256) void gate_rms_kernel(
    const bf16* __restrict__ y,   // [BL][2048]
    bf16* g,                      // [BL][GPAD]: gate pre-act in, normalized y out
    const float* __restrict__ norm_w)
{
    __shared__ float red[4];
    int row = blockIdx.x, t = threadIdx.x;
    const bf16* yr = y + (size_t)row * DINNER;
    bf16* gr = g + (size_t)row * GPAD;
    int c0 = t * 8;
    bf16x8 yv8 = *reinterpret_cast<const bf16x8*>(yr + c0);
    bf16x8 gv8 = *reinterpret_cast<const bf16x8*>(gr + c0);
    float v[8];
#pragma unroll
    for (int i = 0; i < 8; i++) {
        float yf = (float)yv8[i];
        float gf = (float)gv8[i];
        v[i] = yf / (1.f + expf(-gf));
    }
    float ss = 0.f;
#pragma unroll
    for (int i = 0; i < 8; i++) ss += v[i] * v[i];
#pragma unroll
    for (int off = 32; off >= 1; off >>= 1) ss += __shfl_xor(ss, off);
    if ((t & 63) == 0) red[t >> 6] = ss;
    __syncthreads();
    ss = red[0] + red[1] + red[2] + red[3];
    float sc = rsqrtf(ss * (1.0f / DINNER) + 1.1920928955078125e-07f);
    float4 na = *reinterpret_cast<const float4*>(norm_w + c0);
    float4 nb = *reinterpret_cast<const float4*>(norm_w + c0 + 4);
    bf16x8 ov;
    ov[0] = (bf16)(v[0] * sc * na.x);
    ov[1] = (bf16)(v[1] * sc * na.y);
    ov[2] = (bf16)(v[2] * sc * na.z);
    ov[3] = (bf16)(v[3] * sc * na.w);
    ov[4] = (bf16)(v[4] * sc * nb.x);
    ov[5] = (bf16)(v[5] * sc * nb.y);
    ov[6] = (bf16)(v[6] * sc * nb.z);
    ov[7] = (bf16)(v[7] * sc * nb.w);
    *reinterpret_cast<bf16x8*>(gr + c0) = ov;
}

// ---------------- launch ----------------
extern "C" void kernel_launch(void* const* d_in, const int* in_sizes, int n_in,
                              void* d_out, int out_size, void* d_ws, size_t ws_size,
                              hipStream_t stream)
{
    const float* u      = (const float*)d_in[0];
    const float* W_in   = (const float*)d_in[1];
    const float* conv_w = (const float*)d_in[2];
    const float* conv_b = (const float*)d_in[3];
    const float* dparam = (const float*)d_in[4];
    const float* W_gate = (const float*)d_in[5];
    const float* norm_w = (const float*)d_in[6];
    const float* W_out  = (const float*)d_in[7];
    float* out = (float*)d_out;

    char* ws = (char*)d_ws;
    size_t off = 0;
    auto alloc = [&](size_t bytes) {
        void* p = ws + off;
        off += (bytes + 255) & ~(size_t)255;
        return p;
    };
    // total ws use: ~173 MB (padded strides)
    bf16*  u_bf  = (bf16*) alloc((size_t)BLROWS * UPAD * 2);     // 17.8 MB
    bf16*  Wt_f  = (bf16*) alloc((size_t)6400 * UPAD * 2);       // 13.9 MB (W_in | pad | W_gate | pad)
    bf16*  Wt_o  = (bf16*) alloc((size_t)DMODEL * GPAD * 2);     // 4.3 MB
    bf16*  z     = (bf16*) alloc((size_t)BLROWS * ZDIM * 2);     // 67.4 MB
    bf16*  g     = (bf16*) alloc((size_t)BLROWS * GPAD * 2);     // 34.6 MB (yn in-place)
    float* lab   = (float*)alloc((size_t)BLROWS * NHEADS * 4);   // 0.5 MB (log a, written by GEMM)
    bf16*  S     = (bf16*) alloc((size_t)BATCH * NCHUNK * NHEADS * HEADDIM * DSTATE * 2); // 33.6 MB
    float* Adec  = (float*)alloc((size_t)BATCH * NHEADS * NCHUNK * 4);                    // 8 KB
    bf16* xy = (bf16*)d_out;   // x/y live in d_out, fully overwritten by final GEMM
    (void)ws_size; (void)in_sizes; (void)n_in; (void)out_size;

    dim3 tb(32, 8);
    cvt_pad_kernel<<<BLROWS, 256, 0, stream>>>(u, u_bf);
    // fused weight: rows 0..4111 = W_in^T, 4112..4223 = 0, 4224..6271 = W_gate^T, 6272..6399 = 0
    transpose_cvt_kernel<<<dim3(4224 / 32, DMODEL / 32), tb, 0, stream>>>(W_in, Wt_f, DMODEL, ZDIM, 4224, UPAD);
    transpose_cvt_kernel<<<dim3(2176 / 32, DMODEL / 32), tb, 0, stream>>>(W_gate, Wt_f + (size_t)4224 * UPAD, DMODEL, DINNER, 2176, UPAD);
    transpose_cvt_kernel<<<dim3(DMODEL / 32, DINNER / 32), tb, 0, stream>>>(W_out, Wt_o, DINNER, DMODEL, DMODEL, GPAD);

    // fused z|g GEMM (+inline la): M=8192 (64 bm), K=1024 @UPAD (32 slices), N=6400 (50 bn)
    gemm_db3_kernel<32, UPAD, 0, 50><<<64 * 50, 256, 0, stream>>>(
        u_bf, Wt_f, z, g, lab, dparam, nullptr);

    conv_silu_kernel<<<(BLROWS * (DINNER / 8) + 255) / 256, 256, 0, stream>>>(z, conv_w, conv_b, xy);

    // chunked scan (SSD matmul form)
    chunk_state_kernel<<<BATCH * NCHUNK * NHEADS, 256, 0, stream>>>(xy, z, lab, S, Adec);
    chunk_carry_kernel<<<(BATCH * NHEADS * HEADDIM * DSTATE) / 256, 256, 0, stream>>>(S, Adec);
    chunk_y_kernel<<<BATCH * NCHUNK * NHEADS, 256, 0, stream>>>(xy, z, lab, S);

    gate_rms_kernel<<<BLROWS, 256, 0, stream>>>(xy, g, norm_w);

    // out = yn @ W_out (f32 out): M=8192 (64 bm), K=2048 @GPAD (64 slices), N=1024 (8 bn)
    gemm_db3_kernel<64, GPAD, 1, 8><<<64 * 8, 256, 0, stream>>>(
        g, Wt_o, nullptr, nullptr, nullptr, nullptr, out);
}

// Round 16
// 331.359 us; speedup vs baseline: 1.1951x; 1.0862x over previous
//
#include <hip/hip_runtime.h>

#define BATCH   2
#define LSEQ    4096
#define DMODEL  1024
#define DINNER  2048
#define NHEADS  16
#define DSTATE  64
#define HEADDIM 128
#define ZDIM    4112
#define BLROWS  (BATCH*LSEQ)   // 8192
#define QCHUNK  64
#define NCHUNK  (LSEQ/QCHUNK)  // 64
#define UPAD    1088           // padded K-stride for u_bf / Wt_f rows
#define GPAD    2112           // padded K-stride for yn(g) / Wt_o rows

#define AS1 __attribute__((address_space(1)))
#define AS3 __attribute__((address_space(3)))

typedef __bf16 bf16;
typedef __bf16 bf16x8 __attribute__((ext_vector_type(8)));
typedef __bf16 bf16x4 __attribute__((ext_vector_type(4)));
typedef float  f32x4  __attribute__((ext_vector_type(4)));

// paired-row LDS swizzle for [R rows][32 bf16] regions (verified conflict-free rounds 8-15)
__device__ __forceinline__ int lds_elem(int row, int c)
{
    return (row >> 1) * 64 + (row & 1) * 32 + (((c ^ ((row >> 1) & 3)) & 3) << 3);
}

// ---------------- fp32 -> bf16 convert with padded row stride ----------------
__global__ void cvt_pad_kernel(const float* __restrict__ in, bf16* __restrict__ out)
{
    int gid = blockIdx.x * 256 + threadIdx.x;   // 8192 rows x 256 quads
    int row = gid >> 8, c4 = (gid & 255) * 4;
    float4 v = *reinterpret_cast<const float4*>(in + (size_t)row * DMODEL + c4);
    bf16x4 o;
    o[0] = (bf16)v.x; o[1] = (bf16)v.y; o[2] = (bf16)v.z; o[3] = (bf16)v.w;
    *reinterpret_cast<bf16x4*>(out + (size_t)row * UPAD + c4) = o;
}

// ---------------- transpose + convert: src[R][C] f32 -> dst[Cpad rows][stride dstS] bf16 ----
__global__ void transpose_cvt_kernel(const float* __restrict__ src, bf16* __restrict__ dst,
                                     int R, int C, int Cpad, int dstS)
{
    __shared__ float tile[32][33];
    int tx = threadIdx.x;   // 0..31
    int ty = threadIdx.y;   // 0..7
    int c0 = blockIdx.x * 32;
    int r0 = blockIdx.y * 32;
#pragma unroll
    for (int q = 0; q < 4; q++) {
        int r = r0 + ty + q * 8;
        int c = c0 + tx;
        float v = 0.f;
        if (r < R && c < C) v = src[(size_t)r * C + c];
        tile[ty + q * 8][tx] = v;
    }
    __syncthreads();
#pragma unroll
    for (int q = 0; q < 4; q++) {
        int oc = c0 + ty + q * 8;   // output row (= original col)
        int orr = r0 + tx;          // output col (= original row)
        if (oc < Cpad && orr < R)
            dst[(size_t)oc * dstS + orr] = (bf16)tile[tx][ty + q * 8];
    }
}

// ======= triple-buffered GEMM (round-15 passing version, unchanged) =======
template<int NSLICE, int KROW, int MODE, int NBN>
__global__ __launch_bounds__(256) void gemm_db3_kernel(
    const bf16* __restrict__ A, const bf16* __restrict__ Bt,
    bf16* __restrict__ z, bf16* __restrict__ g, float* __restrict__ lab,
    const float* __restrict__ dparam, float* __restrict__ c32)
{
    constexpr int SLOTSZ = 256 * 32;                 // 8192 bf16 = 16 KB
    __shared__ __align__(16) bf16 lds[3 * SLOTSZ];   // 48 KB
    const int tid = threadIdx.x;
    const int lane = tid & 63, wid = tid >> 6;
    const int wm = (wid >> 1) * 64, wn = (wid & 1) * 64;
    const int lml = lane & 15, kc = lane >> 4;

    const int bid = blockIdx.x;
    const int xcd = bid & 7;
    const int idx = bid >> 3;
    const int bm = xcd * 8 + (idx & 7);
    const int bn = idx >> 3;

    const bf16* Abase = A + (size_t)(bm * 128) * KROW;
    const bf16* Bbase = Bt + (size_t)(bn * 128) * KROW;

#define STAGE8(pp) do {                                                                  \
    const int _p = (pp); const int _slot = _p % 3; const size_t _ko = (size_t)_p * 32;   \
    _Pragma("unroll") for (int it = 0; it < 4; ++it) {                                   \
        int q = it * 256 + tid;                                                          \
        int o = (q < 512) ? q : q - 512;                                                 \
        int prow = o >> 3, wi = o & 7;                                                   \
        int row = prow * 2 + (wi >> 2), c = (wi & 3) ^ (prow & 3);                       \
        const bf16* _src = ((q < 512) ? Abase : Bbase) + (size_t)row * KROW + _ko + c * 8; \
        int _dst = _slot * SLOTSZ + ((q < 512) ? 0 : 4096) + o * 8;                      \
        __builtin_amdgcn_global_load_lds((const AS1 void*)_src,                          \
            (AS3 void*)(&lds[_dst]), 16, 0, 0);                                          \
    }                                                                                    \
} while (0)

    f32x4 acc[4][4];
#pragma unroll
    for (int i = 0; i < 4; i++)
#pragma unroll
        for (int j = 0; j < 4; j++) acc[i][j] = (f32x4){0.f, 0.f, 0.f, 0.f};

    STAGE8(0); STAGE8(1); STAGE8(2);
    asm volatile("s_waitcnt vmcnt(8)" ::: "memory");   // slot 0 landed (1,2 in flight)
    __builtin_amdgcn_s_barrier();

    for (int p = 0; p < NSLICE; ++p) {
        const bf16* base_ = &lds[(p % 3) * SLOTSZ];
        bf16x8 af[4], bfv[4];
#pragma unroll
        for (int i = 0; i < 4; ++i) {
            int row = wm + i * 16 + lml;
            af[i] = *reinterpret_cast<const bf16x8*>(&base_[lds_elem(row, kc)]);
        }
#pragma unroll
        for (int j = 0; j < 4; ++j) {
            int row = wn + j * 16 + lml;
            bfv[j] = *reinterpret_cast<const bf16x8*>(&base_[4096 + lds_elem(row, kc)]);
        }
        asm volatile("s_waitcnt lgkmcnt(0)" ::: "memory");
        __builtin_amdgcn_sched_barrier(0);
        __builtin_amdgcn_s_barrier();        // slot p fully consumed by all waves
        if (p + 3 < NSLICE) STAGE8(p + 3);   // refill the just-freed slot
#pragma unroll
        for (int i = 0; i < 4; ++i)
#pragma unroll
            for (int j = 0; j < 4; ++j)
                acc[i][j] = __builtin_amdgcn_mfma_f32_16x16x32_bf16(af[i], bfv[j], acc[i][j], 0, 0, 0);
        if (p + 1 < NSLICE) {
            if (p + 3 < NSLICE)       { asm volatile("s_waitcnt vmcnt(8)" ::: "memory"); }
            else if (p + 2 < NSLICE)  { asm volatile("s_waitcnt vmcnt(4)" ::: "memory"); }
            else                      { asm volatile("s_waitcnt vmcnt(0)" ::: "memory"); }
            __builtin_amdgcn_s_barrier();
        }
    }
#undef STAGE8

    const int rbase = (lane >> 4) * 4;
#pragma unroll
    for (int i = 0; i < 4; i++) {
#pragma unroll
        for (int j = 0; j < 4; j++) {
            int col = bn * 128 + wn + j * 16 + lml;
            if constexpr (MODE == 0) {
                bool isZ = (col < ZDIM);
                bool isG = (col >= 4224) && (col < 4224 + DINNER);
                bool isDT = (col >= 4096) && (col < ZDIM);
                if (!isZ && !isG) continue;
#pragma unroll
                for (int r = 0; r < 4; r++) {
                    int row = bm * 128 + wm + i * 16 + rbase + r;
                    float v = acc[i][j][r];
                    if (isZ) {
                        z[(size_t)row * ZDIM + col] = (bf16)v;
                        if (isDT) {
                            int h = col - 4096;
                            float v2 = v + dparam[h];
                            float sp = (v2 > 20.f) ? v2 : log1pf(expf(v2));
                            lab[(size_t)row * NHEADS + h] = -sp * fabsf(v);
                        }
                    } else {
                        g[(size_t)row * GPAD + (col - 4224)] = (bf16)v;
                    }
                }
            } else {
#pragma unroll
                for (int r = 0; r < 4; r++) {
                    int row = bm * 128 + wm + i * 16 + rbase + r;
                    c32[(size_t)row * 1024 + col] = acc[i][j][r];
                }
            }
        }
    }
}

// ================= chunked scan, SSD matmul form, conv+SiLU fused in =================
// Conv helper: thread owns 4 t-rows x 8 d-cols; computes silu(conv4(z)) into xa[4][8].
// Pass 1: S_c[d][s] = sum_t x[t,d]*(w_t B[t,s])
__global__ __launch_bounds__(256) void chunk_state_kernel(
    const bf16* __restrict__ zz,   // z base (x cols 0..2047, B at 2048+h*64), stride ZDIM
    const float* __restrict__ conv_w, const float* __restrict__ conv_b,
    const float* __restrict__ la,  // [BL][16] log a
    bf16* __restrict__ S,          // [B][NCHUNK][NHEADS][128*64]
    float* __restrict__ Adec)      // [B][NHEADS][NCHUNK] = exp(Ls_Q)
{
    __shared__ __align__(16) bf16 xt[HEADDIM * QCHUNK]; // [d][t] swizzled
    __shared__ __align__(16) bf16 bw[DSTATE * QCHUNK];  // [s][t] swizzled, weighted
    __shared__ float Ls[QCHUNK];
    const int blk = blockIdx.x;
    const int h = blk & 15, c = (blk >> 4) & 63, b = blk >> 10;
    const int tid = threadIdx.x, lane = tid & 63, w = tid >> 6;
    const size_t row0 = (size_t)b * LSEQ + (size_t)c * QCHUNK;
    const bf16* zxg = zz + row0 * ZDIM + h * HEADDIM;
    const bf16* Bg  = zz + row0 * ZDIM + DINNER + h * DSTATE;

    // ---- fused conv+SiLU: thread = (tg 4 t-rows) x (dg8 8 d-cols) ----
    const int tg = (tid >> 4) * 4;
    const int dg8 = (tid & 15) * 8;
    float wv[8][4], xa[4][8];
#pragma unroll
    for (int e = 0; e < 8; e++) {
        float4 w4 = *reinterpret_cast<const float4*>(conv_w + (size_t)(h * HEADDIM + dg8 + e) * 4);
        wv[e][0] = w4.x; wv[e][1] = w4.y; wv[e][2] = w4.z; wv[e][3] = w4.w;
        float bb = conv_b[h * HEADDIM + dg8 + e];
#pragma unroll
        for (int tt = 0; tt < 4; tt++) xa[tt][e] = bb;
    }
#pragma unroll
    for (int r = 0; r < 7; r++) {
        int lrow = c * QCHUNK + tg + r - 3;      // local index within this batch sequence
        if (lrow >= 0) {
            bf16x8 zv = *reinterpret_cast<const bf16x8*>(zxg + (ptrdiff_t)(tg + r - 3) * ZDIM + dg8);
#pragma unroll
            for (int tt = 0; tt < 4; tt++) {
                int k = r - tt;
                if (k >= 0 && k < 4) {
#pragma unroll
                    for (int e = 0; e < 8; e++)
                        xa[tt][e] = fmaf((float)zv[e], wv[e][k], xa[tt][e]);
                }
            }
        }
    }
#pragma unroll
    for (int tt = 0; tt < 4; tt++)
#pragma unroll
        for (int e = 0; e < 8; e++)
            xa[tt][e] = xa[tt][e] / (1.f + expf(-xa[tt][e]));

    // ---- B loads (original mapping) + log-decay cumsum ----
    const int t = tid >> 2, sseg = (tid & 3) * 16;
    bf16x8 br[2];
#pragma unroll
    for (int q = 0; q < 2; q++)
        br[q] = *reinterpret_cast<const bf16x8*>(Bg + (size_t)t * ZDIM + sseg + q * 8);

    if (w == 0) {
        float v = la[(row0 + lane) * NHEADS + h];
#pragma unroll
        for (int off = 1; off < 64; off <<= 1) { float o = __shfl_up(v, off); if (lane >= off) v += o; }
        Ls[lane] = v;
        if (lane == 63) Adec[((size_t)b * NHEADS + h) * NCHUNK + c] = __expf(v);
    }
    __syncthreads();
    const float wt = __expf(Ls[QCHUNK - 1] - Ls[t]);
    // write conv results transposed into xt
#pragma unroll
    for (int tt = 0; tt < 4; tt++) {
        int t2 = tg + tt;
#pragma unroll
        for (int e = 0; e < 8; e++) {
            int d = dg8 + e;
            xt[d * 64 + (((t2 >> 3) ^ (d & 7)) << 3) + (t2 & 7)] = (bf16)xa[tt][e];
        }
    }
    const int tb = t >> 3, ti = t & 7;
#pragma unroll
    for (int q = 0; q < 2; q++)
#pragma unroll
        for (int j = 0; j < 8; j++) {
            int s = sseg + q * 8 + j;
            bw[s * 64 + ((tb ^ (s & 7)) << 3) + ti] = (bf16)((float)br[q][j] * wt);
        }
    __syncthreads();

    f32x4 acc[2][4];
#pragma unroll
    for (int i = 0; i < 2; i++)
#pragma unroll
        for (int j = 0; j < 4; j++) acc[i][j] = (f32x4){0.f, 0.f, 0.f, 0.f};
#pragma unroll
    for (int kk = 0; kk < 2; kk++) {
        const int kb = kk * 4 + (lane >> 4);
        bf16x8 af[2], bf2[4];
#pragma unroll
        for (int i = 0; i < 2; i++) {
            int d = w * 32 + i * 16 + (lane & 15);
            af[i] = *reinterpret_cast<const bf16x8*>(&xt[d * 64 + ((kb ^ (d & 7)) << 3)]);
        }
#pragma unroll
        for (int j = 0; j < 4; j++) {
            int s = j * 16 + (lane & 15);
            bf2[j] = *reinterpret_cast<const bf16x8*>(&bw[s * 64 + ((kb ^ (s & 7)) << 3)]);
        }
#pragma unroll
        for (int i = 0; i < 2; i++)
#pragma unroll
            for (int j = 0; j < 4; j++)
                acc[i][j] = __builtin_amdgcn_mfma_f32_16x16x32_bf16(af[i], bf2[j], acc[i][j], 0, 0, 0);
    }
    bf16* Sg = S + ((size_t)(b * NCHUNK + c) * NHEADS + h) * (HEADDIM * DSTATE);
    const int rr = (lane >> 4) * 4, ccol = lane & 15;
#pragma unroll
    for (int i = 0; i < 2; i++)
#pragma unroll
        for (int j = 0; j < 4; j++)
#pragma unroll
            for (int r = 0; r < 4; r++)
                Sg[(w * 32 + i * 16 + rr + r) * 64 + j * 16 + ccol] = (bf16)acc[i][j][r];
}

// Pass 1b: inter-chunk carry, in-place: S_c -> H_c (state at chunk START).
__global__ void chunk_carry_kernel(bf16* S, const float* __restrict__ A)
{
    int gid = blockIdx.x * 256 + threadIdx.x;
    if (gid >= BATCH * NHEADS * HEADDIM * DSTATE) return;
    int es = gid & (HEADDIM * DSTATE - 1);
    int h  = (gid >> 13) & (NHEADS - 1);
    int b  = gid >> 17;
    const float* Ab = A + ((size_t)b * NHEADS + h) * NCHUNK;
    float hstate = 0.f;
    size_t stride = (size_t)NHEADS * HEADDIM * DSTATE;
    bf16* p = S + ((size_t)b * NCHUNK * NHEADS + h) * (HEADDIM * DSTATE) + es;
    for (int c = 0; c < NCHUNK; ++c) {
        float sv = (float)*p;
        *p = (bf16)hstate;
        hstate = fmaf(Ab[c], hstate, sv);
        p += stride;
    }
}

// Pass 2: Y^T[d][t] = [Xt | H] @ [MG | P.C]^T, conv+SiLU fused; y -> yout.
__global__ __launch_bounds__(256) void chunk_y_kernel(
    bf16* __restrict__ yout,        // [BL][DINNER]: y out
    const bf16* __restrict__ zz,    // z base (x cols + B/C), stride ZDIM
    const float* __restrict__ conv_w, const float* __restrict__ conv_b,
    const float* __restrict__ la,   // [BL][16] log a
    const bf16* __restrict__ H)     // [B][NCHUNK][NHEADS][128*64] chunk-start state
{
    __shared__ __align__(16) bf16 bc[QCHUNK * 128];    // B | C, later MG[64][128]
    __shared__ __align__(16) bf16 xt[HEADDIM * QCHUNK];
    __shared__ __align__(16) bf16 hl[HEADDIM * DSTATE];
    __shared__ float Ls[QCHUNK];
    const int blk = blockIdx.x;
    const int h = blk & 15, c = (blk >> 4) & 63, b = blk >> 10;
    const int tid = threadIdx.x, lane = tid & 63, w = tid >> 6;
    const size_t row0 = (size_t)b * LSEQ + (size_t)c * QCHUNK;
    bf16* yg = yout + row0 * DINNER + h * HEADDIM;
    const bf16* zxg = zz + row0 * ZDIM + h * HEADDIM;
    const bf16* Bg = zz + row0 * ZDIM + DINNER + h * DSTATE;
    const bf16* Cg = Bg + NHEADS * DSTATE;
    const bf16* Hg = H + ((size_t)(b * NCHUNK + c) * NHEADS + h) * (HEADDIM * DSTATE);

#pragma unroll
    for (int it = 0; it < 2; it++) {
        int idx = it * 256 + tid;
        int row = idx >> 3, p = idx & 7;
        int sc = (p ^ (row & 7)) << 3;
        __builtin_amdgcn_global_load_lds((const AS1 void*)(Bg + (size_t)row * ZDIM + sc),
                                         (AS3 void*)(&bc[idx * 8]), 16, 0, 0);
        __builtin_amdgcn_global_load_lds((const AS1 void*)(Cg + (size_t)row * ZDIM + sc),
                                         (AS3 void*)(&bc[4096 + idx * 8]), 16, 0, 0);
    }
#pragma unroll
    for (int it = 0; it < 4; it++) {
        int idx = it * 256 + tid;
        int d = idx >> 3, p = idx & 7;
        __builtin_amdgcn_global_load_lds((const AS1 void*)(Hg + d * 64 + ((p ^ (d & 7)) << 3)),
                                         (AS3 void*)(&hl[idx * 8]), 16, 0, 0);
    }

    // ---- fused conv+SiLU (same mapping as chunk_state) ----
    const int tg = (tid >> 4) * 4;
    const int dg8 = (tid & 15) * 8;
    float wv[8][4], xa[4][8];
#pragma unroll
    for (int e = 0; e < 8; e++) {
        float4 w4 = *reinterpret_cast<const float4*>(conv_w + (size_t)(h * HEADDIM + dg8 + e) * 4);
        wv[e][0] = w4.x; wv[e][1] = w4.y; wv[e][2] = w4.z; wv[e][3] = w4.w;
        float bb = conv_b[h * HEADDIM + dg8 + e];
#pragma unroll
        for (int tt = 0; tt < 4; tt++) xa[tt][e] = bb;
    }
#pragma unroll
    for (int r = 0; r < 7; r++) {
        int lrow = c * QCHUNK + tg + r - 3;
        if (lrow >= 0) {
            bf16x8 zv = *reinterpret_cast<const bf16x8*>(zxg + (ptrdiff_t)(tg + r - 3) * ZDIM + dg8);
#pragma unroll
            for (int tt = 0; tt < 4; tt++) {
                int k = r - tt;
                if (k >= 0 && k < 4) {
#pragma unroll
                    for (int e = 0; e < 8; e++)
                        xa[tt][e] = fmaf((float)zv[e], wv[e][k], xa[tt][e]);
                }
            }
        }
    }
#pragma unroll
    for (int tt = 0; tt < 4; tt++)
#pragma unroll
        for (int e = 0; e < 8; e++)
            xa[tt][e] = xa[tt][e] / (1.f + expf(-xa[tt][e]));

    const int t = tid >> 2, sseg = (tid & 3) * 16;
    if (w == 0) {
        float v = la[(row0 + lane) * NHEADS + h];
#pragma unroll
        for (int off = 1; off < 64; off <<= 1) { float o = __shfl_up(v, off); if (lane >= off) v += o; }
        Ls[lane] = v;
    }
    __syncthreads();

    // write conv results transposed into xt
#pragma unroll
    for (int tt = 0; tt < 4; tt++) {
        int t2 = tg + tt;
#pragma unroll
        for (int e = 0; e < 8; e++) {
            int d = dg8 + e;
            xt[d * 64 + (((t2 >> 3) ^ (d & 7)) << 3) + (t2 & 7)] = (bf16)xa[tt][e];
        }
    }

    // MFMA1: G[t][t'] = sum_s C[t,s] B[t',s]
    f32x4 g[4];
#pragma unroll
    for (int j = 0; j < 4; j++) g[j] = (f32x4){0.f, 0.f, 0.f, 0.f};
#pragma unroll
    for (int kk = 0; kk < 2; kk++) {
        const int kb = kk * 4 + (lane >> 4);
        const int tA = w * 16 + (lane & 15);
        bf16x8 ca = *reinterpret_cast<const bf16x8*>(&bc[4096 + tA * 64 + ((kb ^ (tA & 7)) << 3)]);
#pragma unroll
        for (int j = 0; j < 4; j++) {
            int tB = j * 16 + (lane & 15);
            bf16x8 bb = *reinterpret_cast<const bf16x8*>(&bc[tB * 64 + ((kb ^ (tB & 7)) << 3)]);
            g[j] = __builtin_amdgcn_mfma_f32_16x16x32_bf16(ca, bb, g[j], 0, 0, 0);
        }
    }
    bf16x8 cr[2];
#pragma unroll
    for (int q = 0; q < 2; q++) {
        int sblk = (sseg >> 3) + q;
        cr[q] = *reinterpret_cast<const bf16x8*>(&bc[4096 + t * 64 + ((sblk ^ (t & 7)) << 3)]);
    }
    const float pscale = __expf(Ls[t]);
    __syncthreads();

    {
        const int tpbase = lane & 15;
        const int tgbase = w * 16 + (lane >> 4) * 4;
        float lst[4];
#pragma unroll
        for (int r = 0; r < 4; r++) lst[r] = Ls[tgbase + r];
#pragma unroll
        for (int j = 0; j < 4; j++) {
            int tp = j * 16 + tpbase;
            float lstp = Ls[tp];
#pragma unroll
            for (int r = 0; r < 4; r++) {
                int tg2 = tgbase + r;
                float mg = (tp <= tg2) ? g[j][r] * __expf(lst[r] - lstp) : 0.f;
                bc[tg2 * 128 + (((tp >> 3) ^ (tg2 & 7)) << 3) + (tp & 7)] = (bf16)mg;
            }
        }
    }
#pragma unroll
    for (int q = 0; q < 2; q++) {
        int sblk = (sseg >> 3) + q;
        bf16x8 o;
#pragma unroll
        for (int j = 0; j < 8; j++) o[j] = (bf16)((float)cr[q][j] * pscale);
        *reinterpret_cast<bf16x8*>(&bc[t * 128 + ((8 + (sblk ^ (t & 7))) << 3)]) = o;
    }
    __syncthreads();

    f32x4 acc[2][4];
#pragma unroll
    for (int i = 0; i < 2; i++)
#pragma unroll
        for (int j = 0; j < 4; j++) acc[i][j] = (f32x4){0.f, 0.f, 0.f, 0.f};
#pragma unroll
    for (int kk = 0; kk < 4; kk++) {
        const int kb = kk * 4 + (lane >> 4);
        bf16x8 af[2];
#pragma unroll
        for (int i = 0; i < 2; i++) {
            int d = w * 32 + i * 16 + (lane & 15);
            if (kk < 2)
                af[i] = *reinterpret_cast<const bf16x8*>(&xt[d * 64 + ((kb ^ (d & 7)) << 3)]);
            else
                af[i] = *reinterpret_cast<const bf16x8*>(&hl[d * 64 + (((kb - 8) ^ (d & 7)) << 3)]);
        }
#pragma unroll
        for (int j = 0; j < 4; j++) {
            int tt = j * 16 + (lane & 15);
            bf16x8 b2 = *reinterpret_cast<const bf16x8*>(&bc[tt * 128 + ((kb ^ (tt & 7)) << 3)]);
#pragma unroll
            for (int i = 0; i < 2; i++)
                acc[i][j] = __builtin_amdgcn_mfma_f32_16x16x32_bf16(af[i], b2, acc[i][j], 0, 0, 0);
        }
    }
#pragma unroll
    for (int i = 0; i < 2; i++)
#pragma unroll
        for (int j = 0; j < 4; j++) {
            int d0 = w * 32 + i * 16 + (lane >> 4) * 4;
            int tt = j * 16 + (lane & 15);
            bf16x4 o;
#pragma unroll
            for (int r = 0; r < 4; r++) o[r] = (bf16)acc[i][j][r];
            *reinterpret_cast<bf16x4*>(yg + (size_t)tt * DINNER + d0) = o;
        }
}

// ---------------- gate (sigmoid) * y, RMS norm, -> bf16 (in-place over g, stride GPAD) ----
__global__ __launch_bounds__(256) void gate_rms_kernel(
    const bf16* __restrict__ y,   // [BL][2048]
    bf16* g,                      // [BL][GPAD]: gate pre-act in, normalized y out
    const float* __restrict__ norm_w)
{
    __shared__ float red[4];
    int row = blockIdx.x, t = threadIdx.x;
    const bf16* yr = y + (size_t)row * DINNER;
    bf16* gr = g + (size_t)row * GPAD;
    int c0 = t * 8;
    bf16x8 yv8 = *reinterpret_cast<const bf16x8*>(yr + c0);
    bf16x8 gv8 = *reinterpret_cast<const bf16x8*>(gr + c0);
    float v[8];
#pragma unroll
    for (int i = 0; i < 8; i++) {
        float yf = (float)yv8[i];
        float gf = (float)gv8[i];
        v[i] = yf / (1.f + expf(-gf));
    }
    float ss = 0.f;
#pragma unroll
    for (int i = 0; i < 8; i++) ss += v[i] * v[i];
#pragma unroll
    for (int off = 32; off >= 1; off >>= 1) ss += __shfl_xor(ss, off);
    if ((t & 63) == 0) red[t >> 6] = ss;
    __syncthreads();
    ss = red[0] + red[1] + red[2] + red[3];
    float sc = rsqrtf(ss * (1.0f / DINNER) + 1.1920928955078125e-07f);
    float4 na = *reinterpret_cast<const float4*>(norm_w + c0);
    float4 nb = *reinterpret_cast<const float4*>(norm_w + c0 + 4);
    bf16x8 ov;
    ov[0] = (bf16)(v[0] * sc * na.x);
    ov[1] = (bf16)(v[1] * sc * na.y);
    ov[2] = (bf16)(v[2] * sc * na.z);
    ov[3] = (bf16)(v[3] * sc * na.w);
    ov[4] = (bf16)(v[4] * sc * nb.x);
    ov[5] = (bf16)(v[5] * sc * nb.y);
    ov[6] = (bf16)(v[6] * sc * nb.z);
    ov[7] = (bf16)(v[7] * sc * nb.w);
    *reinterpret_cast<bf16x8*>(gr + c0) = ov;
}

// ---------------- launch ----------------
extern "C" void kernel_launch(void* const* d_in, const int* in_sizes, int n_in,
                              void* d_out, int out_size, void* d_ws, size_t ws_size,
                              hipStream_t stream)
{
    const float* u      = (const float*)d_in[0];
    const float* W_in   = (const float*)d_in[1];
    const float* conv_w = (const float*)d_in[2];
    const float* conv_b = (const float*)d_in[3];
    const float* dparam = (const float*)d_in[4];
    const float* W_gate = (const float*)d_in[5];
    const float* norm_w = (const float*)d_in[6];
    const float* W_out  = (const float*)d_in[7];
    float* out = (float*)d_out;

    char* ws = (char*)d_ws;
    size_t off = 0;
    auto alloc = [&](size_t bytes) {
        void* p = ws + off;
        off += (bytes + 255) & ~(size_t)255;
        return p;
    };
    // total ws use: ~173 MB (padded strides)
    bf16*  u_bf  = (bf16*) alloc((size_t)BLROWS * UPAD * 2);     // 17.8 MB
    bf16*  Wt_f  = (bf16*) alloc((size_t)6400 * UPAD * 2);       // 13.9 MB (W_in | pad | W_gate | pad)
    bf16*  Wt_o  = (bf16*) alloc((size_t)DMODEL * GPAD * 2);     // 4.3 MB
    bf16*  z     = (bf16*) alloc((size_t)BLROWS * ZDIM * 2);     // 67.4 MB
    bf16*  g     = (bf16*) alloc((size_t)BLROWS * GPAD * 2);     // 34.6 MB (yn in-place)
    float* lab   = (float*)alloc((size_t)BLROWS * NHEADS * 4);   // 0.5 MB (log a, written by GEMM)
    bf16*  S     = (bf16*) alloc((size_t)BATCH * NCHUNK * NHEADS * HEADDIM * DSTATE * 2); // 33.6 MB
    float* Adec  = (float*)alloc((size_t)BATCH * NHEADS * NCHUNK * 4);                    // 8 KB
    bf16* xy = (bf16*)d_out;   // y lives in d_out, fully overwritten by final GEMM
    (void)ws_size; (void)in_sizes; (void)n_in; (void)out_size;

    dim3 tb(32, 8);
    cvt_pad_kernel<<<BLROWS, 256, 0, stream>>>(u, u_bf);
    // fused weight: rows 0..4111 = W_in^T, 4112..4223 = 0, 4224..6271 = W_gate^T, 6272..6399 = 0
    transpose_cvt_kernel<<<dim3(4224 / 32, DMODEL / 32), tb, 0, stream>>>(W_in, Wt_f, DMODEL, ZDIM, 4224, UPAD);
    transpose_cvt_kernel<<<dim3(2176 / 32, DMODEL / 32), tb, 0, stream>>>(W_gate, Wt_f + (size_t)4224 * UPAD, DMODEL, DINNER, 2176, UPAD);
    transpose_cvt_kernel<<<dim3(DMODEL / 32, DINNER / 32), tb, 0, stream>>>(W_out, Wt_o, DINNER, DMODEL, DMODEL, GPAD);

    // fused z|g GEMM (+inline la): M=8192 (64 bm), K=1024 @UPAD (32 slices), N=6400 (50 bn)
    gemm_db3_kernel<32, UPAD, 0, 50><<<64 * 50, 256, 0, stream>>>(
        u_bf, Wt_f, z, g, lab, dparam, nullptr);

    // chunked scan (SSD matmul form) with conv+SiLU fused into both passes
    chunk_state_kernel<<<BATCH * NCHUNK * NHEADS, 256, 0, stream>>>(z, conv_w, conv_b, lab, S, Adec);
    chunk_carry_kernel<<<(BATCH * NHEADS * HEADDIM * DSTATE) / 256, 256, 0, stream>>>(S, Adec);
    chunk_y_kernel<<<BATCH * NCHUNK * NHEADS, 256, 0, stream>>>(xy, z, conv_w, conv_b, lab, S);

    gate_rms_kernel<<<BLROWS, 256, 0, stream>>>(xy, g, norm_w);

    // out = yn @ W_out (f32 out): M=8192 (64 bm), K=2048 @GPAD (64 slices), N=1024 (8 bn)
    gemm_db3_kernel<64, GPAD, 1, 8><<<64 * 8, 256, 0, stream>>>(
        g, Wt_o, nullptr, nullptr, nullptr, nullptr, out);
}

// Round 17
// 321.704 us; speedup vs baseline: 1.2309x; 1.0300x over previous
//
#include <hip/hip_runtime.h>

#define BATCH   2
#define LSEQ    4096
#define DMODEL  1024
#define DINNER  2048
#define NHEADS  16
#define DSTATE  64
#define HEADDIM 128
#define ZDIM    4112
#define BLROWS  (BATCH*LSEQ)   // 8192
#define QCHUNK  64
#define NCHUNK  (LSEQ/QCHUNK)  // 64
#define UPAD    1088           // padded K-stride for u_bf / Wt_f rows
#define GPAD    2112           // padded K-stride for v(g) / Wt_o rows

#define AS1 __attribute__((address_space(1)))
#define AS3 __attribute__((address_space(3)))

typedef __bf16 bf16;
typedef __bf16 bf16x8 __attribute__((ext_vector_type(8)));
typedef __bf16 bf16x4 __attribute__((ext_vector_type(4)));
typedef float  f32x4  __attribute__((ext_vector_type(4)));

// paired-row LDS swizzle for [R rows][32 bf16] regions (verified conflict-free rounds 8-16)
__device__ __forceinline__ int lds_elem(int row, int c)
{
    return (row >> 1) * 64 + (row & 1) * 32 + (((c ^ ((row >> 1) & 3)) & 3) << 3);
}

// ---------------- fp32 -> bf16 convert with padded row stride ----------------
__global__ void cvt_pad_kernel(const float* __restrict__ in, bf16* __restrict__ out)
{
    int gid = blockIdx.x * 256 + threadIdx.x;   // 8192 rows x 256 quads
    int row = gid >> 8, c4 = (gid & 255) * 4;
    float4 v = *reinterpret_cast<const float4*>(in + (size_t)row * DMODEL + c4);
    bf16x4 o;
    o[0] = (bf16)v.x; o[1] = (bf16)v.y; o[2] = (bf16)v.z; o[3] = (bf16)v.w;
    *reinterpret_cast<bf16x4*>(out + (size_t)row * UPAD + c4) = o;
}

// ---------------- transpose + convert (+optional per-source-row scale) ----------------
__global__ void transpose_cvt_kernel(const float* __restrict__ src, bf16* __restrict__ dst,
                                     int R, int C, int Cpad, int dstS,
                                     const float* __restrict__ rowscale)
{
    __shared__ float tile[32][33];
    int tx = threadIdx.x;   // 0..31
    int ty = threadIdx.y;   // 0..7
    int c0 = blockIdx.x * 32;
    int r0 = blockIdx.y * 32;
#pragma unroll
    for (int q = 0; q < 4; q++) {
        int r = r0 + ty + q * 8;
        int c = c0 + tx;
        float v = 0.f;
        if (r < R && c < C) v = src[(size_t)r * C + c];
        tile[ty + q * 8][tx] = v;
    }
    __syncthreads();
    float sc = 1.f;
    if (rowscale && (r0 + tx) < R) sc = rowscale[r0 + tx];
#pragma unroll
    for (int q = 0; q < 4; q++) {
        int oc = c0 + ty + q * 8;   // output row (= original col)
        int orr = r0 + tx;          // output col (= original row)
        if (oc < Cpad && orr < R)
            dst[(size_t)oc * dstS + orr] = (bf16)(tile[tx][ty + q * 8] * sc);
    }
}

// ======= triple-buffered GEMM (round-15/16 passing version) =======
// MODE 0: fused z|g epilogue + inline la(dt).  MODE 1: f32 C[M][1024] scaled by rs[row].
template<int NSLICE, int KROW, int MODE, int NBN>
__global__ __launch_bounds__(256) void gemm_db3_kernel(
    const bf16* __restrict__ A, const bf16* __restrict__ Bt,
    bf16* __restrict__ z, bf16* __restrict__ g, float* __restrict__ lab,
    const float* __restrict__ dparam, const float* __restrict__ rs, float* __restrict__ c32)
{
    constexpr int SLOTSZ = 256 * 32;                 // 8192 bf16 = 16 KB
    __shared__ __align__(16) bf16 lds[3 * SLOTSZ];   // 48 KB
    const int tid = threadIdx.x;
    const int lane = tid & 63, wid = tid >> 6;
    const int wm = (wid >> 1) * 64, wn = (wid & 1) * 64;
    const int lml = lane & 15, kc = lane >> 4;

    const int bid = blockIdx.x;
    const int xcd = bid & 7;
    const int idx = bid >> 3;
    const int bm = xcd * 8 + (idx & 7);
    const int bn = idx >> 3;

    const bf16* Abase = A + (size_t)(bm * 128) * KROW;
    const bf16* Bbase = Bt + (size_t)(bn * 128) * KROW;

#define STAGE8(pp) do {                                                                  \
    const int _p = (pp); const int _slot = _p % 3; const size_t _ko = (size_t)_p * 32;   \
    _Pragma("unroll") for (int it = 0; it < 4; ++it) {                                   \
        int q = it * 256 + tid;                                                          \
        int o = (q < 512) ? q : q - 512;                                                 \
        int prow = o >> 3, wi = o & 7;                                                   \
        int row = prow * 2 + (wi >> 2), c = (wi & 3) ^ (prow & 3);                       \
        const bf16* _src = ((q < 512) ? Abase : Bbase) + (size_t)row * KROW + _ko + c * 8; \
        int _dst = _slot * SLOTSZ + ((q < 512) ? 0 : 4096) + o * 8;                      \
        __builtin_amdgcn_global_load_lds((const AS1 void*)_src,                          \
            (AS3 void*)(&lds[_dst]), 16, 0, 0);                                          \
    }                                                                                    \
} while (0)

    f32x4 acc[4][4];
#pragma unroll
    for (int i = 0; i < 4; i++)
#pragma unroll
        for (int j = 0; j < 4; j++) acc[i][j] = (f32x4){0.f, 0.f, 0.f, 0.f};

    STAGE8(0); STAGE8(1); STAGE8(2);
    asm volatile("s_waitcnt vmcnt(8)" ::: "memory");   // slot 0 landed (1,2 in flight)
    __builtin_amdgcn_s_barrier();

    for (int p = 0; p < NSLICE; ++p) {
        const bf16* base_ = &lds[(p % 3) * SLOTSZ];
        bf16x8 af[4], bfv[4];
#pragma unroll
        for (int i = 0; i < 4; ++i) {
            int row = wm + i * 16 + lml;
            af[i] = *reinterpret_cast<const bf16x8*>(&base_[lds_elem(row, kc)]);
        }
#pragma unroll
        for (int j = 0; j < 4; ++j) {
            int row = wn + j * 16 + lml;
            bfv[j] = *reinterpret_cast<const bf16x8*>(&base_[4096 + lds_elem(row, kc)]);
        }
        asm volatile("s_waitcnt lgkmcnt(0)" ::: "memory");
        __builtin_amdgcn_sched_barrier(0);
        __builtin_amdgcn_s_barrier();        // slot p fully consumed by all waves
        if (p + 3 < NSLICE) STAGE8(p + 3);   // refill the just-freed slot
#pragma unroll
        for (int i = 0; i < 4; ++i)
#pragma unroll
            for (int j = 0; j < 4; ++j)
                acc[i][j] = __builtin_amdgcn_mfma_f32_16x16x32_bf16(af[i], bfv[j], acc[i][j], 0, 0, 0);
        if (p + 1 < NSLICE) {
            if (p + 3 < NSLICE)       { asm volatile("s_waitcnt vmcnt(8)" ::: "memory"); }
            else if (p + 2 < NSLICE)  { asm volatile("s_waitcnt vmcnt(4)" ::: "memory"); }
            else                      { asm volatile("s_waitcnt vmcnt(0)" ::: "memory"); }
            __builtin_amdgcn_s_barrier();
        }
    }
#undef STAGE8

    const int rbase = (lane >> 4) * 4;
#pragma unroll
    for (int i = 0; i < 4; i++) {
#pragma unroll
        for (int j = 0; j < 4; j++) {
            int col = bn * 128 + wn + j * 16 + lml;
            if constexpr (MODE == 0) {
                bool isZ = (col < ZDIM);
                bool isG = (col >= 4224) && (col < 4224 + DINNER);
                bool isDT = (col >= 4096) && (col < ZDIM);
                if (!isZ && !isG) continue;
#pragma unroll
                for (int r = 0; r < 4; r++) {
                    int row = bm * 128 + wm + i * 16 + rbase + r;
                    float v = acc[i][j][r];
                    if (isZ) {
                        z[(size_t)row * ZDIM + col] = (bf16)v;
                        if (isDT) {
                            int h = col - 4096;
                            float v2 = v + dparam[h];
                            float sp = (v2 > 20.f) ? v2 : log1pf(expf(v2));
                            lab[(size_t)row * NHEADS + h] = -sp * fabsf(v);
                        }
                    } else {
                        g[(size_t)row * GPAD + (col - 4224)] = (bf16)v;
                    }
                }
            } else {
                int row0 = bm * 128 + wm + i * 16 + rbase;
                float4 rsv = *reinterpret_cast<const float4*>(rs + row0);
                const float* rp = reinterpret_cast<const float*>(&rsv);
#pragma unroll
                for (int r = 0; r < 4; r++)
                    c32[(size_t)(row0 + r) * 1024 + col] = acc[i][j][r] * rp[r];
            }
        }
    }
}

// ================= chunked scan, SSD matmul form, conv+SiLU fused in =================
__global__ __launch_bounds__(256) void chunk_state_kernel(
    const bf16* __restrict__ zz,   // z base (x cols 0..2047, B at 2048+h*64), stride ZDIM
    const float* __restrict__ conv_w, const float* __restrict__ conv_b,
    const float* __restrict__ la,  // [BL][16] log a
    bf16* __restrict__ S,          // [B][NCHUNK][NHEADS][128*64]
    float* __restrict__ Adec)      // [B][NHEADS][NCHUNK] = exp(Ls_Q)
{
    __shared__ __align__(16) bf16 xt[HEADDIM * QCHUNK]; // [d][t] swizzled
    __shared__ __align__(16) bf16 bw[DSTATE * QCHUNK];  // [s][t] swizzled, weighted
    __shared__ float Ls[QCHUNK];
    const int blk = blockIdx.x;
    const int h = blk & 15, c = (blk >> 4) & 63, b = blk >> 10;
    const int tid = threadIdx.x, lane = tid & 63, w = tid >> 6;
    const size_t row0 = (size_t)b * LSEQ + (size_t)c * QCHUNK;
    const bf16* zxg = zz + row0 * ZDIM + h * HEADDIM;
    const bf16* Bg  = zz + row0 * ZDIM + DINNER + h * DSTATE;

    // ---- fused conv+SiLU: thread = (tg 4 t-rows) x (dg8 8 d-cols) ----
    const int tg = (tid >> 4) * 4;
    const int dg8 = (tid & 15) * 8;
    float wv[8][4], xa[4][8];
#pragma unroll
    for (int e = 0; e < 8; e++) {
        float4 w4 = *reinterpret_cast<const float4*>(conv_w + (size_t)(h * HEADDIM + dg8 + e) * 4);
        wv[e][0] = w4.x; wv[e][1] = w4.y; wv[e][2] = w4.z; wv[e][3] = w4.w;
        float bb = conv_b[h * HEADDIM + dg8 + e];
#pragma unroll
        for (int tt = 0; tt < 4; tt++) xa[tt][e] = bb;
    }
#pragma unroll
    for (int r = 0; r < 7; r++) {
        int lrow = c * QCHUNK + tg + r - 3;      // local index within this batch sequence
        if (lrow >= 0) {
            bf16x8 zv = *reinterpret_cast<const bf16x8*>(zxg + (ptrdiff_t)(tg + r - 3) * ZDIM + dg8);
#pragma unroll
            for (int tt = 0; tt < 4; tt++) {
                int k = r - tt;
                if (k >= 0 && k < 4) {
#pragma unroll
                    for (int e = 0; e < 8; e++)
                        xa[tt][e] = fmaf((float)zv[e], wv[e][k], xa[tt][e]);
                }
            }
        }
    }
#pragma unroll
    for (int tt = 0; tt < 4; tt++)
#pragma unroll
        for (int e = 0; e < 8; e++)
            xa[tt][e] = xa[tt][e] / (1.f + expf(-xa[tt][e]));

    const int t = tid >> 2, sseg = (tid & 3) * 16;
    bf16x8 br[2];
#pragma unroll
    for (int q = 0; q < 2; q++)
        br[q] = *reinterpret_cast<const bf16x8*>(Bg + (size_t)t * ZDIM + sseg + q * 8);

    if (w == 0) {
        float v = la[(row0 + lane) * NHEADS + h];
#pragma unroll
        for (int off = 1; off < 64; off <<= 1) { float o = __shfl_up(v, off); if (lane >= off) v += o; }
        Ls[lane] = v;
        if (lane == 63) Adec[((size_t)b * NHEADS + h) * NCHUNK + c] = __expf(v);
    }
    __syncthreads();
    const float wt = __expf(Ls[QCHUNK - 1] - Ls[t]);
#pragma unroll
    for (int tt = 0; tt < 4; tt++) {
        int t2 = tg + tt;
#pragma unroll
        for (int e = 0; e < 8; e++) {
            int d = dg8 + e;
            xt[d * 64 + (((t2 >> 3) ^ (d & 7)) << 3) + (t2 & 7)] = (bf16)xa[tt][e];
        }
    }
    const int tb = t >> 3, ti = t & 7;
#pragma unroll
    for (int q = 0; q < 2; q++)
#pragma unroll
        for (int j = 0; j < 8; j++) {
            int s = sseg + q * 8 + j;
            bw[s * 64 + ((tb ^ (s & 7)) << 3) + ti] = (bf16)((float)br[q][j] * wt);
        }
    __syncthreads();

    f32x4 acc[2][4];
#pragma unroll
    for (int i = 0; i < 2; i++)
#pragma unroll
        for (int j = 0; j < 4; j++) acc[i][j] = (f32x4){0.f, 0.f, 0.f, 0.f};
#pragma unroll
    for (int kk = 0; kk < 2; kk++) {
        const int kb = kk * 4 + (lane >> 4);
        bf16x8 af[2], bf2[4];
#pragma unroll
        for (int i = 0; i < 2; i++) {
            int d = w * 32 + i * 16 + (lane & 15);
            af[i] = *reinterpret_cast<const bf16x8*>(&xt[d * 64 + ((kb ^ (d & 7)) << 3)]);
        }
#pragma unroll
        for (int j = 0; j < 4; j++) {
            int s = j * 16 + (lane & 15);
            bf2[j] = *reinterpret_cast<const bf16x8*>(&bw[s * 64 + ((kb ^ (s & 7)) << 3)]);
        }
#pragma unroll
        for (int i = 0; i < 2; i++)
#pragma unroll
            for (int j = 0; j < 4; j++)
                acc[i][j] = __builtin_amdgcn_mfma_f32_16x16x32_bf16(af[i], bf2[j], acc[i][j], 0, 0, 0);
    }
    bf16* Sg = S + ((size_t)(b * NCHUNK + c) * NHEADS + h) * (HEADDIM * DSTATE);
    const int rr = (lane >> 4) * 4, ccol = lane & 15;
#pragma unroll
    for (int i = 0; i < 2; i++)
#pragma unroll
        for (int j = 0; j < 4; j++)
#pragma unroll
            for (int r = 0; r < 4; r++)
                Sg[(w * 32 + i * 16 + rr + r) * 64 + j * 16 + ccol] = (bf16)acc[i][j][r];
}

// Pass 1b: inter-chunk carry, in-place: S_c -> H_c (state at chunk START).
__global__ void chunk_carry_kernel(bf16* S, const float* __restrict__ A)
{
    int gid = blockIdx.x * 256 + threadIdx.x;
    if (gid >= BATCH * NHEADS * HEADDIM * DSTATE) return;
    int es = gid & (HEADDIM * DSTATE - 1);
    int h  = (gid >> 13) & (NHEADS - 1);
    int b  = gid >> 17;
    const float* Ab = A + ((size_t)b * NHEADS + h) * NCHUNK;
    float hstate = 0.f;
    size_t stride = (size_t)NHEADS * HEADDIM * DSTATE;
    bf16* p = S + ((size_t)b * NCHUNK * NHEADS + h) * (HEADDIM * DSTATE) + es;
    for (int c = 0; c < NCHUNK; ++c) {
        float sv = (float)*p;
        *p = (bf16)hstate;
        hstate = fmaf(Ab[c], hstate, sv);
        p += stride;
    }
}

// Pass 2: Y^T[d][t] = [Xt | H] @ [MG | P.C]^T, conv+SiLU fused; epilogue applies the
// gate (v = y*sigmoid(g), written in-place over g) and emits per-(row,head) sum(v^2).
__global__ __launch_bounds__(256) void chunk_y_kernel(
    bf16* __restrict__ gv,          // [BL][GPAD]: gate pre-act in, gated v out (in-place)
    const bf16* __restrict__ zz,    // z base (x cols + B/C), stride ZDIM
    const float* __restrict__ conv_w, const float* __restrict__ conv_b,
    const float* __restrict__ la,   // [BL][16] log a
    const bf16* __restrict__ H,     // [B][NCHUNK][NHEADS][128*64] chunk-start state
    float* __restrict__ psum)       // [BL][NHEADS] per-head sum(v^2)
{
    __shared__ __align__(16) bf16 bc[QCHUNK * 128];    // B | C, later MG[64][128]
    __shared__ __align__(16) bf16 xt[HEADDIM * QCHUNK];
    __shared__ __align__(16) bf16 hl[HEADDIM * DSTATE];
    __shared__ float Ls[QCHUNK];
    __shared__ float wsum[4][QCHUNK];
    const int blk = blockIdx.x;
    const int h = blk & 15, c = (blk >> 4) & 63, b = blk >> 10;
    const int tid = threadIdx.x, lane = tid & 63, w = tid >> 6;
    const size_t row0 = (size_t)b * LSEQ + (size_t)c * QCHUNK;
    bf16* gg = gv + row0 * GPAD + h * HEADDIM;
    const bf16* zxg = zz + row0 * ZDIM + h * HEADDIM;
    const bf16* Bg = zz + row0 * ZDIM + DINNER + h * DSTATE;
    const bf16* Cg = Bg + NHEADS * DSTATE;
    const bf16* Hg = H + ((size_t)(b * NCHUNK + c) * NHEADS + h) * (HEADDIM * DSTATE);

#pragma unroll
    for (int it = 0; it < 2; it++) {
        int idx = it * 256 + tid;
        int row = idx >> 3, p = idx & 7;
        int sc = (p ^ (row & 7)) << 3;
        __builtin_amdgcn_global_load_lds((const AS1 void*)(Bg + (size_t)row * ZDIM + sc),
                                         (AS3 void*)(&bc[idx * 8]), 16, 0, 0);
        __builtin_amdgcn_global_load_lds((const AS1 void*)(Cg + (size_t)row * ZDIM + sc),
                                         (AS3 void*)(&bc[4096 + idx * 8]), 16, 0, 0);
    }
#pragma unroll
    for (int it = 0; it < 4; it++) {
        int idx = it * 256 + tid;
        int d = idx >> 3, p = idx & 7;
        __builtin_amdgcn_global_load_lds((const AS1 void*)(Hg + d * 64 + ((p ^ (d & 7)) << 3)),
                                         (AS3 void*)(&hl[idx * 8]), 16, 0, 0);
    }

    // ---- fused conv+SiLU ----
    const int tg = (tid >> 4) * 4;
    const int dg8 = (tid & 15) * 8;
    float wv[8][4], xa[4][8];
#pragma unroll
    for (int e = 0; e < 8; e++) {
        float4 w4 = *reinterpret_cast<const float4*>(conv_w + (size_t)(h * HEADDIM + dg8 + e) * 4);
        wv[e][0] = w4.x; wv[e][1] = w4.y; wv[e][2] = w4.z; wv[e][3] = w4.w;
        float bb = conv_b[h * HEADDIM + dg8 + e];
#pragma unroll
        for (int tt = 0; tt < 4; tt++) xa[tt][e] = bb;
    }
#pragma unroll
    for (int r = 0; r < 7; r++) {
        int lrow = c * QCHUNK + tg + r - 3;
        if (lrow >= 0) {
            bf16x8 zv = *reinterpret_cast<const bf16x8*>(zxg + (ptrdiff_t)(tg + r - 3) * ZDIM + dg8);
#pragma unroll
            for (int tt = 0; tt < 4; tt++) {
                int k = r - tt;
                if (k >= 0 && k < 4) {
#pragma unroll
                    for (int e = 0; e < 8; e++)
                        xa[tt][e] = fmaf((float)zv[e], wv[e][k], xa[tt][e]);
                }
            }
        }
    }
#pragma unroll
    for (int tt = 0; tt < 4; tt++)
#pragma unroll
        for (int e = 0; e < 8; e++)
            xa[tt][e] = xa[tt][e] / (1.f + expf(-xa[tt][e]));

    const int t = tid >> 2, sseg = (tid & 3) * 16;
    if (w == 0) {
        float v = la[(row0 + lane) * NHEADS + h];
#pragma unroll
        for (int off = 1; off < 64; off <<= 1) { float o = __shfl_up(v, off); if (lane >= off) v += o; }
        Ls[lane] = v;
    }
    __syncthreads();

#pragma unroll
    for (int tt = 0; tt < 4; tt++) {
        int t2 = tg + tt;
#pragma unroll
        for (int e = 0; e < 8; e++) {
            int d = dg8 + e;
            xt[d * 64 + (((t2 >> 3) ^ (d & 7)) << 3) + (t2 & 7)] = (bf16)xa[tt][e];
        }
    }

    // MFMA1: G[t][t'] = sum_s C[t,s] B[t',s]
    f32x4 g[4];
#pragma unroll
    for (int j = 0; j < 4; j++) g[j] = (f32x4){0.f, 0.f, 0.f, 0.f};
#pragma unroll
    for (int kk = 0; kk < 2; kk++) {
        const int kb = kk * 4 + (lane >> 4);
        const int tA = w * 16 + (lane & 15);
        bf16x8 ca = *reinterpret_cast<const bf16x8*>(&bc[4096 + tA * 64 + ((kb ^ (tA & 7)) << 3)]);
#pragma unroll
        for (int j = 0; j < 4; j++) {
            int tB = j * 16 + (lane & 15);
            bf16x8 bb = *reinterpret_cast<const bf16x8*>(&bc[tB * 64 + ((kb ^ (tB & 7)) << 3)]);
            g[j] = __builtin_amdgcn_mfma_f32_16x16x32_bf16(ca, bb, g[j], 0, 0, 0);
        }
    }
    bf16x8 cr[2];
#pragma unroll
    for (int q = 0; q < 2; q++) {
        int sblk = (sseg >> 3) + q;
        cr[q] = *reinterpret_cast<const bf16x8*>(&bc[4096 + t * 64 + ((sblk ^ (t & 7)) << 3)]);
    }
    const float pscale = __expf(Ls[t]);
    __syncthreads();

    {
        const int tpbase = lane & 15;
        const int tgbase = w * 16 + (lane >> 4) * 4;
        float lst[4];
#pragma unroll
        for (int r = 0; r < 4; r++) lst[r] = Ls[tgbase + r];
#pragma unroll
        for (int j = 0; j < 4; j++) {
            int tp = j * 16 + tpbase;
            float lstp = Ls[tp];
#pragma unroll
            for (int r = 0; r < 4; r++) {
                int tg2 = tgbase + r;
                float mg = (tp <= tg2) ? g[j][r] * __expf(lst[r] - lstp) : 0.f;
                bc[tg2 * 128 + (((tp >> 3) ^ (tg2 & 7)) << 3) + (tp & 7)] = (bf16)mg;
            }
        }
    }
#pragma unroll
    for (int q = 0; q < 2; q++) {
        int sblk = (sseg >> 3) + q;
        bf16x8 o;
#pragma unroll
        for (int j = 0; j < 8; j++) o[j] = (bf16)((float)cr[q][j] * pscale);
        *reinterpret_cast<bf16x8*>(&bc[t * 128 + ((8 + (sblk ^ (t & 7))) << 3)]) = o;
    }
    __syncthreads();

    f32x4 acc[2][4];
#pragma unroll
    for (int i = 0; i < 2; i++)
#pragma unroll
        for (int j = 0; j < 4; j++) acc[i][j] = (f32x4){0.f, 0.f, 0.f, 0.f};
#pragma unroll
    for (int kk = 0; kk < 4; kk++) {
        const int kb = kk * 4 + (lane >> 4);
        bf16x8 af[2];
#pragma unroll
        for (int i = 0; i < 2; i++) {
            int d = w * 32 + i * 16 + (lane & 15);
            if (kk < 2)
                af[i] = *reinterpret_cast<const bf16x8*>(&xt[d * 64 + ((kb ^ (d & 7)) << 3)]);
            else
                af[i] = *reinterpret_cast<const bf16x8*>(&hl[d * 64 + (((kb - 8) ^ (d & 7)) << 3)]);
        }
#pragma unroll
        for (int j = 0; j < 4; j++) {
            int tt = j * 16 + (lane & 15);
            bf16x8 b2 = *reinterpret_cast<const bf16x8*>(&bc[tt * 128 + ((kb ^ (tt & 7)) << 3)]);
#pragma unroll
            for (int i = 0; i < 2; i++)
                acc[i][j] = __builtin_amdgcn_mfma_f32_16x16x32_bf16(af[i], b2, acc[i][j], 0, 0, 0);
        }
    }

    // ---- epilogue: v = y * sigmoid(gate); write v in-place; accumulate row sum(v^2) ----
    float ps[4] = {0.f, 0.f, 0.f, 0.f};
#pragma unroll
    for (int i = 0; i < 2; i++)
#pragma unroll
        for (int j = 0; j < 4; j++) {
            int d0 = w * 32 + i * 16 + (lane >> 4) * 4;
            int tt = j * 16 + (lane & 15);
            bf16x4 gt = *reinterpret_cast<const bf16x4*>(gg + (size_t)tt * GPAD + d0);
            bf16x4 o;
#pragma unroll
            for (int r = 0; r < 4; r++) {
                float gf = (float)gt[r];
                float vv = acc[i][j][r] / (1.f + expf(-gf));
                o[r] = (bf16)vv;
                ps[j] = fmaf(vv, vv, ps[j]);
            }
            *reinterpret_cast<bf16x4*>(gg + (size_t)tt * GPAD + d0) = o;
        }
    // reduce over lane>>4 (4 lanes share same rows within a wave)
#pragma unroll
    for (int j = 0; j < 4; j++) {
        ps[j] += __shfl_xor(ps[j], 16);
        ps[j] += __shfl_xor(ps[j], 32);
    }
    if ((lane >> 4) == 0) {
#pragma unroll
        for (int j = 0; j < 4; j++) wsum[w][j * 16 + (lane & 15)] = ps[j];
    }
    __syncthreads();
    if (tid < QCHUNK) {
        float tot = wsum[0][tid] + wsum[1][tid] + wsum[2][tid] + wsum[3][tid];
        psum[(row0 + tid) * NHEADS + h] = tot;
    }
}

// ---------------- rowscale: rs[r] = rsqrt(mean(sum_h psum) + eps) ----------------
__global__ void rowscale_kernel(const float* __restrict__ psum, float* __restrict__ rs)
{
    int r = blockIdx.x * 256 + threadIdx.x;
    if (r >= BLROWS) return;
    float s = 0.f;
#pragma unroll
    for (int h = 0; h < NHEADS; h++) s += psum[(size_t)r * NHEADS + h];
    rs[r] = rsqrtf(s * (1.0f / DINNER) + 1.1920928955078125e-07f);
}

// ---------------- launch ----------------
extern "C" void kernel_launch(void* const* d_in, const int* in_sizes, int n_in,
                              void* d_out, int out_size, void* d_ws, size_t ws_size,
                              hipStream_t stream)
{
    const float* u      = (const float*)d_in[0];
    const float* W_in   = (const float*)d_in[1];
    const float* conv_w = (const float*)d_in[2];
    const float* conv_b = (const float*)d_in[3];
    const float* dparam = (const float*)d_in[4];
    const float* W_gate = (const float*)d_in[5];
    const float* norm_w = (const float*)d_in[6];
    const float* W_out  = (const float*)d_in[7];
    float* out = (float*)d_out;

    char* ws = (char*)d_ws;
    size_t off = 0;
    auto alloc = [&](size_t bytes) {
        void* p = ws + off;
        off += (bytes + 255) & ~(size_t)255;
        return p;
    };
    // total ws use: ~174 MB (padded strides)
    bf16*  u_bf  = (bf16*) alloc((size_t)BLROWS * UPAD * 2);     // 17.8 MB
    bf16*  Wt_f  = (bf16*) alloc((size_t)6400 * UPAD * 2);       // 13.9 MB (W_in | pad | W_gate | pad)
    bf16*  Wt_o  = (bf16*) alloc((size_t)DMODEL * GPAD * 2);     // 4.3 MB (norm_w folded in)
    bf16*  z     = (bf16*) alloc((size_t)BLROWS * ZDIM * 2);     // 67.4 MB
    bf16*  g     = (bf16*) alloc((size_t)BLROWS * GPAD * 2);     // 34.6 MB (gate in, v in-place)
    float* lab   = (float*)alloc((size_t)BLROWS * NHEADS * 4);   // 0.5 MB (log a, written by GEMM)
    bf16*  S     = (bf16*) alloc((size_t)BATCH * NCHUNK * NHEADS * HEADDIM * DSTATE * 2); // 33.6 MB
    float* Adec  = (float*)alloc((size_t)BATCH * NHEADS * NCHUNK * 4);                    // 8 KB
    float* psum  = (float*)alloc((size_t)BLROWS * NHEADS * 4);   // 0.5 MB
    float* rs    = (float*)alloc((size_t)BLROWS * 4);            // 32 KB
    (void)ws_size; (void)in_sizes; (void)n_in; (void)out_size;

    dim3 tb(32, 8);
    cvt_pad_kernel<<<BLROWS, 256, 0, stream>>>(u, u_bf);
    // fused weight: rows 0..4111 = W_in^T, 4112..4223 = 0, 4224..6271 = W_gate^T, 6272..6399 = 0
    transpose_cvt_kernel<<<dim3(4224 / 32, DMODEL / 32), tb, 0, stream>>>(W_in, Wt_f, DMODEL, ZDIM, 4224, UPAD, nullptr);
    transpose_cvt_kernel<<<dim3(2176 / 32, DMODEL / 32), tb, 0, stream>>>(W_gate, Wt_f + (size_t)4224 * UPAD, DMODEL, DINNER, 2176, UPAD, nullptr);
    // W_out transpose with norm_w folded into the K (source-row) axis
    transpose_cvt_kernel<<<dim3(DMODEL / 32, DINNER / 32), tb, 0, stream>>>(W_out, Wt_o, DINNER, DMODEL, DMODEL, GPAD, norm_w);

    // fused z|g GEMM (+inline la): M=8192 (64 bm), K=1024 @UPAD (32 slices), N=6400 (50 bn)
    gemm_db3_kernel<32, UPAD, 0, 50><<<64 * 50, 256, 0, stream>>>(
        u_bf, Wt_f, z, g, lab, dparam, nullptr, nullptr);

    // chunked scan (SSD matmul form) with conv+SiLU fused; chunk_y also applies the gate
    chunk_state_kernel<<<BATCH * NCHUNK * NHEADS, 256, 0, stream>>>(z, conv_w, conv_b, lab, S, Adec);
    chunk_carry_kernel<<<(BATCH * NHEADS * HEADDIM * DSTATE) / 256, 256, 0, stream>>>(S, Adec);
    chunk_y_kernel<<<BATCH * NCHUNK * NHEADS, 256, 0, stream>>>(g, z, conv_w, conv_b, lab, S, psum);

    rowscale_kernel<<<(BLROWS + 255) / 256, 256, 0, stream>>>(psum, rs);

    // out = (v * rs) @ (norm_w-folded W_out): M=8192, K=2048 @GPAD (64 slices), N=1024 (8 bn)
    gemm_db3_kernel<64, GPAD, 1, 8><<<64 * 8, 256, 0, stream>>>(
        g, Wt_o, nullptr, nullptr, nullptr, nullptr, rs, out);
}

// Round 18
// 313.367 us; speedup vs baseline: 1.2637x; 1.0266x over previous
//
#include <hip/hip_runtime.h>

#define BATCH   2
#define LSEQ    4096
#define DMODEL  1024
#define DINNER  2048
#define NHEADS  16
#define DSTATE  64
#define HEADDIM 128
#define ZDIM    4112
#define BLROWS  (BATCH*LSEQ)   // 8192
#define QCHUNK  64
#define NCHUNK  (LSEQ/QCHUNK)  // 64
#define UPAD    1088           // padded K-stride for u_bf / Wt_f rows
#define GPAD    2112           // padded K-stride for v(g) / Wt_o rows
#define NGATE0  4112           // first gate column in fused N
#define NFUSE2  6272           // 4112(z) + 2048(g) + 112(pad), 49*128

#define AS1 __attribute__((address_space(1)))
#define AS3 __attribute__((address_space(3)))

typedef __bf16 bf16;
typedef __bf16 bf16x8 __attribute__((ext_vector_type(8)));
typedef __bf16 bf16x4 __attribute__((ext_vector_type(4)));
typedef float  f32x4  __attribute__((ext_vector_type(4)));

// paired-row LDS swizzle for [R rows][32 bf16] regions (verified conflict-free rounds 8-17)
__device__ __forceinline__ int lds_elem(int row, int c)
{
    return (row >> 1) * 64 + (row & 1) * 32 + (((c ^ ((row >> 1) & 3)) & 3) << 3);
}

// ---------------- merged prologue: cvt_pad + 3 transposes, flat block ranges ----------------
__device__ __forceinline__ void do_transpose(const float* __restrict__ src, bf16* __restrict__ dst,
                                             int R, int C, int Cpad, int dstS,
                                             const float* __restrict__ rowscale,
                                             int bx, int by, int tid)
{
    __shared__ float tile[32][33];
    int tx = tid & 31, ty = tid >> 5;
    int c0 = bx * 32, r0 = by * 32;
#pragma unroll
    for (int q = 0; q < 4; q++) {
        int r = r0 + ty + q * 8;
        int c = c0 + tx;
        float v = 0.f;
        if (r < R && c < C) v = src[(size_t)r * C + c];
        tile[ty + q * 8][tx] = v;
    }
    __syncthreads();
    float sc = 1.f;
    if (rowscale && (r0 + tx) < R) sc = rowscale[r0 + tx];
#pragma unroll
    for (int q = 0; q < 4; q++) {
        int oc = c0 + ty + q * 8;   // output row (= original col)
        int orr = r0 + tx;          // output col (= original row)
        if (oc < Cpad && orr < R)
            dst[(size_t)oc * dstS + orr] = (bf16)(tile[tx][ty + q * 8] * sc);
    }
}

#define PREP_CVT   8192
#define PREP_WIN   (PREP_CVT + 129 * 32)     // 4128 blocks (Cpad 4112)
#define PREP_WG    (PREP_WIN + 68 * 32)      // 2176 blocks (Cpad 2160)
#define PREP_WO    (PREP_WG + 32 * 64)       // 2048 blocks
__global__ __launch_bounds__(256) void prep_kernel(
    const float* __restrict__ u, const float* __restrict__ W_in,
    const float* __restrict__ W_gate, const float* __restrict__ W_out,
    const float* __restrict__ norm_w,
    bf16* __restrict__ u_bf, bf16* __restrict__ Wt_f, bf16* __restrict__ Wt_o)
{
    int b = blockIdx.x, tid = threadIdx.x;
    if (b < PREP_CVT) {
        int row = b, c4 = tid * 4;
        float4 v = *reinterpret_cast<const float4*>(u + (size_t)row * DMODEL + c4);
        bf16x4 o;
        o[0] = (bf16)v.x; o[1] = (bf16)v.y; o[2] = (bf16)v.z; o[3] = (bf16)v.w;
        *reinterpret_cast<bf16x4*>(u_bf + (size_t)row * UPAD + c4) = o;
    } else if (b < PREP_WIN) {
        int t = b - PREP_CVT;
        do_transpose(W_in, Wt_f, DMODEL, ZDIM, NGATE0, UPAD, nullptr, t % 129, t / 129, tid);
    } else if (b < PREP_WG) {
        int t = b - PREP_WIN;
        do_transpose(W_gate, Wt_f + (size_t)NGATE0 * UPAD, DMODEL, DINNER, 2160, UPAD, nullptr,
                     t % 68, t / 68, tid);
    } else {
        int t = b - PREP_WG;
        do_transpose(W_out, Wt_o, DINNER, DMODEL, DMODEL, GPAD, norm_w, t & 31, t >> 5, tid);
    }
}

// ======= triple-buffered GEMM =======
// MODE 0: fused z|g epilogue + inline la(dt).  MODE 1: f32 C[M][1024] scaled by
// rs[row] computed in-kernel from psum (rowscale folded in).
template<int NSLICE, int KROW, int MODE, int NBN>
__global__ __launch_bounds__(256) void gemm_db3_kernel(
    const bf16* __restrict__ A, const bf16* __restrict__ Bt,
    bf16* __restrict__ z, bf16* __restrict__ g, float* __restrict__ lab,
    const float* __restrict__ dparam, const float* __restrict__ psum, float* __restrict__ c32)
{
    constexpr int SLOTSZ = 256 * 32;                 // 8192 bf16 = 16 KB
    __shared__ __align__(16) bf16 lds[3 * SLOTSZ];   // 48 KB
    __shared__ float srs[128];
    const int tid = threadIdx.x;
    const int lane = tid & 63, wid = tid >> 6;
    const int wm = (wid >> 1) * 64, wn = (wid & 1) * 64;
    const int lml = lane & 15, kc = lane >> 4;

    const int bid = blockIdx.x;
    const int xcd = bid & 7;
    const int idx = bid >> 3;
    const int bm = xcd * 8 + (idx & 7);
    const int bn = idx >> 3;

    const bf16* Abase = A + (size_t)(bm * 128) * KROW;
    const bf16* Bbase = Bt + (size_t)(bn * 128) * KROW;

#define STAGE8(pp) do {                                                                  \
    const int _p = (pp); const int _slot = _p % 3; const size_t _ko = (size_t)_p * 32;   \
    _Pragma("unroll") for (int it = 0; it < 4; ++it) {                                   \
        int q = it * 256 + tid;                                                          \
        int o = (q < 512) ? q : q - 512;                                                 \
        int prow = o >> 3, wi = o & 7;                                                   \
        int row = prow * 2 + (wi >> 2), c = (wi & 3) ^ (prow & 3);                       \
        const bf16* _src = ((q < 512) ? Abase : Bbase) + (size_t)row * KROW + _ko + c * 8; \
        int _dst = _slot * SLOTSZ + ((q < 512) ? 0 : 4096) + o * 8;                      \
        __builtin_amdgcn_global_load_lds((const AS1 void*)_src,                          \
            (AS3 void*)(&lds[_dst]), 16, 0, 0);                                          \
    }                                                                                    \
} while (0)

    // MODE 1: fold rowscale — psum loads issued BEFORE stage loads so the prologue
    // vmcnt(8) drains psum + slot 0 and leaves slots 1,2 in flight (ledger preserved).
    if constexpr (MODE == 1) {
        if (tid < 128) {
            int row = bm * 128 + tid;
            float s = 0.f;
#pragma unroll
            for (int h = 0; h < NHEADS; h++) s += psum[(size_t)row * NHEADS + h];
            srs[tid] = rsqrtf(s * (1.0f / DINNER) + 1.1920928955078125e-07f);
        }
    }

    f32x4 acc[4][4];
#pragma unroll
    for (int i = 0; i < 4; i++)
#pragma unroll
        for (int j = 0; j < 4; j++) acc[i][j] = (f32x4){0.f, 0.f, 0.f, 0.f};

    STAGE8(0); STAGE8(1); STAGE8(2);
    asm volatile("s_waitcnt vmcnt(8)" ::: "memory");   // slot 0 (and psum) landed
    __builtin_amdgcn_s_barrier();

    for (int p = 0; p < NSLICE; ++p) {
        const bf16* base_ = &lds[(p % 3) * SLOTSZ];
        bf16x8 af[4], bfv[4];
#pragma unroll
        for (int i = 0; i < 4; ++i) {
            int row = wm + i * 16 + lml;
            af[i] = *reinterpret_cast<const bf16x8*>(&base_[lds_elem(row, kc)]);
        }
#pragma unroll
        for (int j = 0; j < 4; ++j) {
            int row = wn + j * 16 + lml;
            bfv[j] = *reinterpret_cast<const bf16x8*>(&base_[4096 + lds_elem(row, kc)]);
        }
        asm volatile("s_waitcnt lgkmcnt(0)" ::: "memory");
        __builtin_amdgcn_sched_barrier(0);
        __builtin_amdgcn_s_barrier();        // slot p fully consumed by all waves
        if (p + 3 < NSLICE) STAGE8(p + 3);   // refill the just-freed slot
#pragma unroll
        for (int i = 0; i < 4; ++i)
#pragma unroll
            for (int j = 0; j < 4; ++j)
                acc[i][j] = __builtin_amdgcn_mfma_f32_16x16x32_bf16(af[i], bfv[j], acc[i][j], 0, 0, 0);
        if (p + 1 < NSLICE) {
            if (p + 3 < NSLICE)       { asm volatile("s_waitcnt vmcnt(8)" ::: "memory"); }
            else if (p + 2 < NSLICE)  { asm volatile("s_waitcnt vmcnt(4)" ::: "memory"); }
            else                      { asm volatile("s_waitcnt vmcnt(0)" ::: "memory"); }
            __builtin_amdgcn_s_barrier();
        }
    }
#undef STAGE8

    const int rbase = (lane >> 4) * 4;
#pragma unroll
    for (int i = 0; i < 4; i++) {
#pragma unroll
        for (int j = 0; j < 4; j++) {
            int col = bn * 128 + wn + j * 16 + lml;
            if constexpr (MODE == 0) {
                bool isZ = (col < ZDIM);
                bool isG = (col >= NGATE0) && (col < NGATE0 + DINNER);
                bool isDT = (col >= 4096) && (col < ZDIM);
                if (!isZ && !isG) continue;
#pragma unroll
                for (int r = 0; r < 4; r++) {
                    int row = bm * 128 + wm + i * 16 + rbase + r;
                    float v = acc[i][j][r];
                    if (isZ) {
                        z[(size_t)row * ZDIM + col] = (bf16)v;
                        if (isDT) {
                            int h = col - 4096;
                            float v2 = v + dparam[h];
                            float sp = (v2 > 20.f) ? v2 : log1pf(expf(v2));
                            lab[(size_t)row * NHEADS + h] = -sp * fabsf(v);
                        }
                    }
                    if (isG) {
                        g[(size_t)row * GPAD + (col - NGATE0)] = (bf16)v;
                    }
                }
            } else {
                int row0 = bm * 128 + wm + i * 16 + rbase;
                int l0 = wm + i * 16 + rbase;
#pragma unroll
                for (int r = 0; r < 4; r++)
                    c32[(size_t)(row0 + r) * 1024 + col] = acc[i][j][r] * srs[l0 + r];
            }
        }
    }
}

// ================= chunked scan, SSD matmul form, conv+SiLU fused in =================
__global__ __launch_bounds__(256) void chunk_state_kernel(
    const bf16* __restrict__ zz,   // z base (x cols 0..2047, B at 2048+h*64), stride ZDIM
    const float* __restrict__ conv_w, const float* __restrict__ conv_b,
    const float* __restrict__ la,  // [BL][16] log a
    bf16* __restrict__ S,          // [B][NCHUNK][NHEADS][128*64]
    float* __restrict__ Adec)      // [B][NHEADS][NCHUNK] = exp(Ls_Q)
{
    __shared__ __align__(16) bf16 xt[HEADDIM * QCHUNK]; // [d][t] swizzled
    __shared__ __align__(16) bf16 bw[DSTATE * QCHUNK];  // [s][t] swizzled, weighted
    __shared__ float Ls[QCHUNK];
    const int blk = blockIdx.x;
    const int h = blk & 15, c = (blk >> 4) & 63, b = blk >> 10;
    const int tid = threadIdx.x, lane = tid & 63, w = tid >> 6;
    const size_t row0 = (size_t)b * LSEQ + (size_t)c * QCHUNK;
    const bf16* zxg = zz + row0 * ZDIM + h * HEADDIM;
    const bf16* Bg  = zz + row0 * ZDIM + DINNER + h * DSTATE;

    // ---- fused conv+SiLU: thread = (tg 4 t-rows) x (dg8 8 d-cols) ----
    const int tg = (tid >> 4) * 4;
    const int dg8 = (tid & 15) * 8;
    float wv[8][4], xa[4][8];
#pragma unroll
    for (int e = 0; e < 8; e++) {
        float4 w4 = *reinterpret_cast<const float4*>(conv_w + (size_t)(h * HEADDIM + dg8 + e) * 4);
        wv[e][0] = w4.x; wv[e][1] = w4.y; wv[e][2] = w4.z; wv[e][3] = w4.w;
        float bb = conv_b[h * HEADDIM + dg8 + e];
#pragma unroll
        for (int tt = 0; tt < 4; tt++) xa[tt][e] = bb;
    }
#pragma unroll
    for (int r = 0; r < 7; r++) {
        int lrow = c * QCHUNK + tg + r - 3;      // local index within this batch sequence
        if (lrow >= 0) {
            bf16x8 zv = *reinterpret_cast<const bf16x8*>(zxg + (ptrdiff_t)(tg + r - 3) * ZDIM + dg8);
#pragma unroll
            for (int tt = 0; tt < 4; tt++) {
                int k = r - tt;
                if (k >= 0 && k < 4) {
#pragma unroll
                    for (int e = 0; e < 8; e++)
                        xa[tt][e] = fmaf((float)zv[e], wv[e][k], xa[tt][e]);
                }
            }
        }
    }
#pragma unroll
    for (int tt = 0; tt < 4; tt++)
#pragma unroll
        for (int e = 0; e < 8; e++)
            xa[tt][e] = xa[tt][e] / (1.f + expf(-xa[tt][e]));

    const int t = tid >> 2, sseg = (tid & 3) * 16;
    bf16x8 br[2];
#pragma unroll
    for (int q = 0; q < 2; q++)
        br[q] = *reinterpret_cast<const bf16x8*>(Bg + (size_t)t * ZDIM + sseg + q * 8);

    if (w == 0) {
        float v = la[(row0 + lane) * NHEADS + h];
#pragma unroll
        for (int off = 1; off < 64; off <<= 1) { float o = __shfl_up(v, off); if (lane >= off) v += o; }
        Ls[lane] = v;
        if (lane == 63) Adec[((size_t)b * NHEADS + h) * NCHUNK + c] = __expf(v);
    }
    __syncthreads();
    const float wt = __expf(Ls[QCHUNK - 1] - Ls[t]);
#pragma unroll
    for (int tt = 0; tt < 4; tt++) {
        int t2 = tg + tt;
#pragma unroll
        for (int e = 0; e < 8; e++) {
            int d = dg8 + e;
            xt[d * 64 + (((t2 >> 3) ^ (d & 7)) << 3) + (t2 & 7)] = (bf16)xa[tt][e];
        }
    }
    const int tb = t >> 3, ti = t & 7;
#pragma unroll
    for (int q = 0; q < 2; q++)
#pragma unroll
        for (int j = 0; j < 8; j++) {
            int s = sseg + q * 8 + j;
            bw[s * 64 + ((tb ^ (s & 7)) << 3) + ti] = (bf16)((float)br[q][j] * wt);
        }
    __syncthreads();

    f32x4 acc[2][4];
#pragma unroll
    for (int i = 0; i < 2; i++)
#pragma unroll
        for (int j = 0; j < 4; j++) acc[i][j] = (f32x4){0.f, 0.f, 0.f, 0.f};
#pragma unroll
    for (int kk = 0; kk < 2; kk++) {
        const int kb = kk * 4 + (lane >> 4);
        bf16x8 af[2], bf2[4];
#pragma unroll
        for (int i = 0; i < 2; i++) {
            int d = w * 32 + i * 16 + (lane & 15);
            af[i] = *reinterpret_cast<const bf16x8*>(&xt[d * 64 + ((kb ^ (d & 7)) << 3)]);
        }
#pragma unroll
        for (int j = 0; j < 4; j++) {
            int s = j * 16 + (lane & 15);
            bf2[j] = *reinterpret_cast<const bf16x8*>(&bw[s * 64 + ((kb ^ (s & 7)) << 3)]);
        }
#pragma unroll
        for (int i = 0; i < 2; i++)
#pragma unroll
            for (int j = 0; j < 4; j++)
                acc[i][j] = __builtin_amdgcn_mfma_f32_16x16x32_bf16(af[i], bf2[j], acc[i][j], 0, 0, 0);
    }
    bf16* Sg = S + ((size_t)(b * NCHUNK + c) * NHEADS + h) * (HEADDIM * DSTATE);
    const int rr = (lane >> 4) * 4, ccol = lane & 15;
#pragma unroll
    for (int i = 0; i < 2; i++)
#pragma unroll
        for (int j = 0; j < 4; j++)
#pragma unroll
            for (int r = 0; r < 4; r++)
                Sg[(w * 32 + i * 16 + rr + r) * 64 + j * 16 + ccol] = (bf16)acc[i][j][r];
}

// Pass 1b: inter-chunk carry, in-place: S_c -> H_c (state at chunk START).
__global__ void chunk_carry_kernel(bf16* S, const float* __restrict__ A)
{
    int gid = blockIdx.x * 256 + threadIdx.x;
    if (gid >= BATCH * NHEADS * HEADDIM * DSTATE) return;
    int es = gid & (HEADDIM * DSTATE - 1);
    int h  = (gid >> 13) & (NHEADS - 1);
    int b  = gid >> 17;
    const float* Ab = A + ((size_t)b * NHEADS + h) * NCHUNK;
    float hstate = 0.f;
    size_t stride = (size_t)NHEADS * HEADDIM * DSTATE;
    bf16* p = S + ((size_t)b * NCHUNK * NHEADS + h) * (HEADDIM * DSTATE) + es;
    for (int c = 0; c < NCHUNK; ++c) {
        float sv = (float)*p;
        *p = (bf16)hstate;
        hstate = fmaf(Ab[c], hstate, sv);
        p += stride;
    }
}

// Pass 2: Y^T[d][t] = [Xt | H] @ [MG | P.C]^T, conv+SiLU fused; epilogue applies the
// gate (v = y*sigmoid(g), written in-place over g) and emits per-(row,head) sum(v^2).
__global__ __launch_bounds__(256) void chunk_y_kernel(
    bf16* __restrict__ gv,          // [BL][GPAD]: gate pre-act in, gated v out (in-place)
    const bf16* __restrict__ zz,    // z base (x cols + B/C), stride ZDIM
    const float* __restrict__ conv_w, const float* __restrict__ conv_b,
    const float* __restrict__ la,   // [BL][16] log a
    const bf16* __restrict__ H,     // [B][NCHUNK][NHEADS][128*64] chunk-start state
    float* __restrict__ psum)       // [BL][NHEADS] per-head sum(v^2)
{
    __shared__ __align__(16) bf16 bc[QCHUNK * 128];    // B | C, later MG[64][128]
    __shared__ __align__(16) bf16 xt[HEADDIM * QCHUNK];
    __shared__ __align__(16) bf16 hl[HEADDIM * DSTATE];
    __shared__ float Ls[QCHUNK];
    __shared__ float wsum[4][QCHUNK];
    const int blk = blockIdx.x;
    const int h = blk & 15, c = (blk >> 4) & 63, b = blk >> 10;
    const int tid = threadIdx.x, lane = tid & 63, w = tid >> 6;
    const size_t row0 = (size_t)b * LSEQ + (size_t)c * QCHUNK;
    bf16* gg = gv + row0 * GPAD + h * HEADDIM;
    const bf16* zxg = zz + row0 * ZDIM + h * HEADDIM;
    const bf16* Bg = zz + row0 * ZDIM + DINNER + h * DSTATE;
    const bf16* Cg = Bg + NHEADS * DSTATE;
    const bf16* Hg = H + ((size_t)(b * NCHUNK + c) * NHEADS + h) * (HEADDIM * DSTATE);

#pragma unroll
    for (int it = 0; it < 2; it++) {
        int idx = it * 256 + tid;
        int row = idx >> 3, p = idx & 7;
        int sc = (p ^ (row & 7)) << 3;
        __builtin_amdgcn_global_load_lds((const AS1 void*)(Bg + (size_t)row * ZDIM + sc),
                                         (AS3 void*)(&bc[idx * 8]), 16, 0, 0);
        __builtin_amdgcn_global_load_lds((const AS1 void*)(Cg + (size_t)row * ZDIM + sc),
                                         (AS3 void*)(&bc[4096 + idx * 8]), 16, 0, 0);
    }
#pragma unroll
    for (int it = 0; it < 4; it++) {
        int idx = it * 256 + tid;
        int d = idx >> 3, p = idx & 7;
        __builtin_amdgcn_global_load_lds((const AS1 void*)(Hg + d * 64 + ((p ^ (d & 7)) << 3)),
                                         (AS3 void*)(&hl[idx * 8]), 16, 0, 0);
    }

    // ---- fused conv+SiLU ----
    const int tg = (tid >> 4) * 4;
    const int dg8 = (tid & 15) * 8;
    float wv[8][4], xa[4][8];
#pragma unroll
    for (int e = 0; e < 8; e++) {
        float4 w4 = *reinterpret_cast<const float4*>(conv_w + (size_t)(h * HEADDIM + dg8 + e) * 4);
        wv[e][0] = w4.x; wv[e][1] = w4.y; wv[e][2] = w4.z; wv[e][3] = w4.w;
        float bb = conv_b[h * HEADDIM + dg8 + e];
#pragma unroll
        for (int tt = 0; tt < 4; tt++) xa[tt][e] = bb;
    }
#pragma unroll
    for (int r = 0; r < 7; r++) {
        int lrow = c * QCHUNK + tg + r - 3;
        if (lrow >= 0) {
            bf16x8 zv = *reinterpret_cast<const bf16x8*>(zxg + (ptrdiff_t)(tg + r - 3) * ZDIM + dg8);
#pragma unroll
            for (int tt = 0; tt < 4; tt++) {
                int k = r - tt;
                if (k >= 0 && k < 4) {
#pragma unroll
                    for (int e = 0; e < 8; e++)
                        xa[tt][e] = fmaf((float)zv[e], wv[e][k], xa[tt][e]);
                }
            }
        }
    }
#pragma unroll
    for (int tt = 0; tt < 4; tt++)
#pragma unroll
        for (int e = 0; e < 8; e++)
            xa[tt][e] = xa[tt][e] / (1.f + expf(-xa[tt][e]));

    const int t = tid >> 2, sseg = (tid & 3) * 16;
    if (w == 0) {
        float v = la[(row0 + lane) * NHEADS + h];
#pragma unroll
        for (int off = 1; off < 64; off <<= 1) { float o = __shfl_up(v, off); if (lane >= off) v += o; }
        Ls[lane] = v;
    }
    __syncthreads();

#pragma unroll
    for (int tt = 0; tt < 4; tt++) {
        int t2 = tg + tt;
#pragma unroll
        for (int e = 0; e < 8; e++) {
            int d = dg8 + e;
            xt[d * 64 + (((t2 >> 3) ^ (d & 7)) << 3) + (t2 & 7)] = (bf16)xa[tt][e];
        }
    }

    // MFMA1: G[t][t'] = sum_s C[t,s] B[t',s]
    f32x4 g[4];
#pragma unroll
    for (int j = 0; j < 4; j++) g[j] = (f32x4){0.f, 0.f, 0.f, 0.f};
#pragma unroll
    for (int kk = 0; kk < 2; kk++) {
        const int kb = kk * 4 + (lane >> 4);
        const int tA = w * 16 + (lane & 15);
        bf16x8 ca = *reinterpret_cast<const bf16x8*>(&bc[4096 + tA * 64 + ((kb ^ (tA & 7)) << 3)]);
#pragma unroll
        for (int j = 0; j < 4; j++) {
            int tB = j * 16 + (lane & 15);
            bf16x8 bb = *reinterpret_cast<const bf16x8*>(&bc[tB * 64 + ((kb ^ (tB & 7)) << 3)]);
            g[j] = __builtin_amdgcn_mfma_f32_16x16x32_bf16(ca, bb, g[j], 0, 0, 0);
        }
    }
    bf16x8 cr[2];
#pragma unroll
    for (int q = 0; q < 2; q++) {
        int sblk = (sseg >> 3) + q;
        cr[q] = *reinterpret_cast<const bf16x8*>(&bc[4096 + t * 64 + ((sblk ^ (t & 7)) << 3)]);
    }
    const float pscale = __expf(Ls[t]);
    __syncthreads();

    {
        const int tpbase = lane & 15;
        const int tgbase = w * 16 + (lane >> 4) * 4;
        float lst[4];
#pragma unroll
        for (int r = 0; r < 4; r++) lst[r] = Ls[tgbase + r];
#pragma unroll
        for (int j = 0; j < 4; j++) {
            int tp = j * 16 + tpbase;
            float lstp = Ls[tp];
#pragma unroll
            for (int r = 0; r < 4; r++) {
                int tg2 = tgbase + r;
                float mg = (tp <= tg2) ? g[j][r] * __expf(lst[r] - lstp) : 0.f;
                bc[tg2 * 128 + (((tp >> 3) ^ (tg2 & 7)) << 3) + (tp & 7)] = (bf16)mg;
            }
        }
    }
#pragma unroll
    for (int q = 0; q < 2; q++) {
        int sblk = (sseg >> 3) + q;
        bf16x8 o;
#pragma unroll
        for (int j = 0; j < 8; j++) o[j] = (bf16)((float)cr[q][j] * pscale);
        *reinterpret_cast<bf16x8*>(&bc[t * 128 + ((8 + (sblk ^ (t & 7))) << 3)]) = o;
    }
    __syncthreads();

    f32x4 acc[2][4];
#pragma unroll
    for (int i = 0; i < 2; i++)
#pragma unroll
        for (int j = 0; j < 4; j++) acc[i][j] = (f32x4){0.f, 0.f, 0.f, 0.f};
#pragma unroll
    for (int kk = 0; kk < 4; kk++) {
        const int kb = kk * 4 + (lane >> 4);
        bf16x8 af[2];
#pragma unroll
        for (int i = 0; i < 2; i++) {
            int d = w * 32 + i * 16 + (lane & 15);
            if (kk < 2)
                af[i] = *reinterpret_cast<const bf16x8*>(&xt[d * 64 + ((kb ^ (d & 7)) << 3)]);
            else
                af[i] = *reinterpret_cast<const bf16x8*>(&hl[d * 64 + (((kb - 8) ^ (d & 7)) << 3)]);
        }
#pragma unroll
        for (int j = 0; j < 4; j++) {
            int tt = j * 16 + (lane & 15);
            bf16x8 b2 = *reinterpret_cast<const bf16x8*>(&bc[tt * 128 + ((kb ^ (tt & 7)) << 3)]);
#pragma unroll
            for (int i = 0; i < 2; i++)
                acc[i][j] = __builtin_amdgcn_mfma_f32_16x16x32_bf16(af[i], b2, acc[i][j], 0, 0, 0);
        }
    }

    // ---- epilogue: v = y * sigmoid(gate); write v in-place; accumulate row sum(v^2) ----
    float ps[4] = {0.f, 0.f, 0.f, 0.f};
#pragma unroll
    for (int i = 0; i < 2; i++)
#pragma unroll
        for (int j = 0; j < 4; j++) {
            int d0 = w * 32 + i * 16 + (lane >> 4) * 4;
            int tt = j * 16 + (lane & 15);
            bf16x4 gt = *reinterpret_cast<const bf16x4*>(gg + (size_t)tt * GPAD + d0);
            bf16x4 o;
#pragma unroll
            for (int r = 0; r < 4; r++) {
                float gf = (float)gt[r];
                float vv = acc[i][j][r] / (1.f + expf(-gf));
                o[r] = (bf16)vv;
                ps[j] = fmaf(vv, vv, ps[j]);
            }
            *reinterpret_cast<bf16x4*>(gg + (size_t)tt * GPAD + d0) = o;
        }
    // reduce over lane>>4 (4 lanes share same rows within a wave)
#pragma unroll
    for (int j = 0; j < 4; j++) {
        ps[j] += __shfl_xor(ps[j], 16);
        ps[j] += __shfl_xor(ps[j], 32);
    }
    if ((lane >> 4) == 0) {
#pragma unroll
        for (int j = 0; j < 4; j++) wsum[w][j * 16 + (lane & 15)] = ps[j];
    }
    __syncthreads();
    if (tid < QCHUNK) {
        float tot = wsum[0][tid] + wsum[1][tid] + wsum[2][tid] + wsum[3][tid];
        psum[(row0 + tid) * NHEADS + h] = tot;
    }
}

// ---------------- launch ----------------
extern "C" void kernel_launch(void* const* d_in, const int* in_sizes, int n_in,
                              void* d_out, int out_size, void* d_ws, size_t ws_size,
                              hipStream_t stream)
{
    const float* u      = (const float*)d_in[0];
    const float* W_in   = (const float*)d_in[1];
    const float* conv_w = (const float*)d_in[2];
    const float* conv_b = (const float*)d_in[3];
    const float* dparam = (const float*)d_in[4];
    const float* W_gate = (const float*)d_in[5];
    const float* norm_w = (const float*)d_in[6];
    const float* W_out  = (const float*)d_in[7];
    float* out = (float*)d_out;

    char* ws = (char*)d_ws;
    size_t off = 0;
    auto alloc = [&](size_t bytes) {
        void* p = ws + off;
        off += (bytes + 255) & ~(size_t)255;
        return p;
    };
    // total ws use: ~174 MB (padded strides)
    bf16*  u_bf  = (bf16*) alloc((size_t)BLROWS * UPAD * 2);     // 17.8 MB
    bf16*  Wt_f  = (bf16*) alloc((size_t)6288 * UPAD * 2);       // 13.7 MB (W_in | W_gate | pad)
    bf16*  Wt_o  = (bf16*) alloc((size_t)DMODEL * GPAD * 2);     // 4.3 MB (norm_w folded in)
    bf16*  z     = (bf16*) alloc((size_t)BLROWS * ZDIM * 2);     // 67.4 MB
    bf16*  g     = (bf16*) alloc((size_t)BLROWS * GPAD * 2);     // 34.6 MB (gate in, v in-place)
    float* lab   = (float*)alloc((size_t)BLROWS * NHEADS * 4);   // 0.5 MB (log a, written by GEMM)
    bf16*  S     = (bf16*) alloc((size_t)BATCH * NCHUNK * NHEADS * HEADDIM * DSTATE * 2); // 33.6 MB
    float* Adec  = (float*)alloc((size_t)BATCH * NHEADS * NCHUNK * 4);                    // 8 KB
    float* psum  = (float*)alloc((size_t)BLROWS * NHEADS * 4);   // 0.5 MB
    (void)ws_size; (void)in_sizes; (void)n_in; (void)out_size;

    // merged prologue: cvt_pad + W_in/W_gate/W_out transposes (norm_w folded into Wt_o)
    prep_kernel<<<PREP_WO, 256, 0, stream>>>(u, W_in, W_gate, W_out, norm_w, u_bf, Wt_f, Wt_o);

    // fused z|g GEMM (+inline la): M=8192 (64 bm), K=1024 @UPAD (32 slices), N=6272 (49 bn)
    gemm_db3_kernel<32, UPAD, 0, 49><<<64 * 49, 256, 0, stream>>>(
        u_bf, Wt_f, z, g, lab, dparam, nullptr, nullptr);

    // chunked scan (SSD matmul form) with conv+SiLU fused; chunk_y also applies the gate
    chunk_state_kernel<<<BATCH * NCHUNK * NHEADS, 256, 0, stream>>>(z, conv_w, conv_b, lab, S, Adec);
    chunk_carry_kernel<<<(BATCH * NHEADS * HEADDIM * DSTATE) / 256, 256, 0, stream>>>(S, Adec);
    chunk_y_kernel<<<BATCH * NCHUNK * NHEADS, 256, 0, stream>>>(g, z, conv_w, conv_b, lab, S, psum);

    // out = (v * rs) @ (norm_w-folded W_out), rowscale computed in-kernel from psum
    gemm_db3_kernel<64, GPAD, 1, 8><<<64 * 8, 256, 0, stream>>>(
        g, Wt_o, nullptr, nullptr, nullptr, nullptr, psum, out);
}

// Round 19
// 286.981 us; speedup vs baseline: 1.3799x; 1.0919x over previous
//
#include <hip/hip_runtime.h>

#define BATCH   2
#define LSEQ    4096
#define DMODEL  1024
#define DINNER  2048
#define NHEADS  16
#define DSTATE  64
#define HEADDIM 128
#define ZDIM    4112
#define BLROWS  (BATCH*LSEQ)   // 8192
#define QCHUNK  64
#define NCHUNK  (LSEQ/QCHUNK)  // 64
#define UPAD    1088           // padded K-stride for u_bf / Wt_f rows
#define GPAD    2112           // padded K-stride for v(g) / Wt_o rows
#define NGATE0  4112           // first gate column in fused N

#define AS1 __attribute__((address_space(1)))
#define AS3 __attribute__((address_space(3)))

typedef __bf16 bf16;
typedef __bf16 bf16x8 __attribute__((ext_vector_type(8)));
typedef __bf16 bf16x4 __attribute__((ext_vector_type(4)));
typedef float  f32x4  __attribute__((ext_vector_type(4)));

// paired-row LDS swizzle for [R rows][32 bf16] regions (verified conflict-free rounds 8-18)
__device__ __forceinline__ int lds_elem(int row, int c)
{
    return (row >> 1) * 64 + (row & 1) * 32 + (((c ^ ((row >> 1) & 3)) & 3) << 3);
}

// ---------------- merged prologue: cvt_pad + 3 transposes, flat block ranges ----------------
__device__ __forceinline__ void do_transpose(const float* __restrict__ src, bf16* __restrict__ dst,
                                             int R, int C, int Cpad, int dstS,
                                             const float* __restrict__ rowscale,
                                             int bx, int by, int tid)
{
    __shared__ float tile[32][33];
    int tx = tid & 31, ty = tid >> 5;
    int c0 = bx * 32, r0 = by * 32;
#pragma unroll
    for (int q = 0; q < 4; q++) {
        int r = r0 + ty + q * 8;
        int c = c0 + tx;
        float v = 0.f;
        if (r < R && c < C) v = src[(size_t)r * C + c];
        tile[ty + q * 8][tx] = v;
    }
    __syncthreads();
    float sc = 1.f;
    if (rowscale && (r0 + tx) < R) sc = rowscale[r0 + tx];
#pragma unroll
    for (int q = 0; q < 4; q++) {
        int oc = c0 + ty + q * 8;   // output row (= original col)
        int orr = r0 + tx;          // output col (= original row)
        if (oc < Cpad && orr < R)
            dst[(size_t)oc * dstS + orr] = (bf16)(tile[tx][ty + q * 8] * sc);
    }
}

#define PREP_CVT   8192
#define PREP_WIN   (PREP_CVT + 129 * 32)     // 4128 blocks (Cpad 4112)
#define PREP_WG    (PREP_WIN + 68 * 32)      // 2176 blocks (Cpad 2160)
#define PREP_WO    (PREP_WG + 32 * 64)       // 2048 blocks
__global__ __launch_bounds__(256) void prep_kernel(
    const float* __restrict__ u, const float* __restrict__ W_in,
    const float* __restrict__ W_gate, const float* __restrict__ W_out,
    const float* __restrict__ norm_w,
    bf16* __restrict__ u_bf, bf16* __restrict__ Wt_f, bf16* __restrict__ Wt_o)
{
    int b = blockIdx.x, tid = threadIdx.x;
    if (b < PREP_CVT) {
        int row = b, c4 = tid * 4;
        float4 v = *reinterpret_cast<const float4*>(u + (size_t)row * DMODEL + c4);
        bf16x4 o;
        o[0] = (bf16)v.x; o[1] = (bf16)v.y; o[2] = (bf16)v.z; o[3] = (bf16)v.w;
        *reinterpret_cast<bf16x4*>(u_bf + (size_t)row * UPAD + c4) = o;
    } else if (b < PREP_WIN) {
        int t = b - PREP_CVT;
        do_transpose(W_in, Wt_f, DMODEL, ZDIM, NGATE0, UPAD, nullptr, t % 129, t / 129, tid);
    } else if (b < PREP_WG) {
        int t = b - PREP_WIN;
        do_transpose(W_gate, Wt_f + (size_t)NGATE0 * UPAD, DMODEL, DINNER, 2160, UPAD, nullptr,
                     t % 68, t / 68, tid);
    } else {
        int t = b - PREP_WG;
        do_transpose(W_out, Wt_o, DINNER, DMODEL, DMODEL, GPAD, norm_w, t & 31, t >> 5, tid);
    }
}

// ======= 2-slot dbuf GEMM, BK=64 (halved phase count): 128x128 tile, 4 waves =======
// Slot = 32KB: { A_k0[128][32], A_k1[128][32], B_k0[128][32], B_k1[128][32] }, each
// region paired-row swizzled. Per phase: 16 ds_read_b128/wave, 32 MFMA/wave over 2 k-halves.
// Schedule (round-9/11-verified family): reads ; lgkm(0) ; barrier ; STAGE(p+2 -> freed
// slot) ; MFMA ; vmcnt(8) [slot p+1 landed, p+2 in flight] ; barrier.  64KB -> 2 blocks/CU.
// MODE 0: fused z|g epilogue + inline la(dt).  MODE 1: f32 C scaled by in-kernel rowscale.
template<int NSLICE, int KROW, int MODE, int NBN>
__global__ __launch_bounds__(256) void gemm_db3_kernel(
    const bf16* __restrict__ A, const bf16* __restrict__ Bt,
    bf16* __restrict__ z, bf16* __restrict__ g, float* __restrict__ lab,
    const float* __restrict__ dparam, const float* __restrict__ psum, float* __restrict__ c32)
{
    constexpr int SLOTSZ = 16384;                    // 32 KB per slot
    __shared__ __align__(16) bf16 lds[2 * SLOTSZ];   // 64 KB
    __shared__ float srs[128];
    const int tid = threadIdx.x;
    const int lane = tid & 63, wid = tid >> 6;
    const int wm = (wid >> 1) * 64, wn = (wid & 1) * 64;
    const int lml = lane & 15, kc = lane >> 4;

    const int bid = blockIdx.x;
    const int xcd = bid & 7;
    const int idx = bid >> 3;
    const int bm = xcd * 8 + (idx & 7);
    const int bn = idx >> 3;

    const bf16* Abase = A + (size_t)(bm * 128) * KROW;
    const bf16* Bbase = Bt + (size_t)(bn * 128) * KROW;

    // one STAGE = 8 global_load_lds per thread (2048 16B-chunks: A_k0|A_k1|B_k0|B_k1)
#define STAGE8(pp) do {                                                                  \
    const int _p = (pp); const int _slot = _p & 1; const size_t _ko = (size_t)_p * 64;   \
    _Pragma("unroll") for (int it = 0; it < 8; ++it) {                                   \
        int q = it * 256 + tid;                                                          \
        int reg = q >> 9;                 /* 0:A_k0 1:A_k1 2:B_k0 3:B_k1 */              \
        int o = q & 511;                                                                 \
        int prow = o >> 3, wi = o & 7;                                                   \
        int row = prow * 2 + (wi >> 2), c = (wi & 3) ^ (prow & 3);                       \
        const bf16* _mb = (reg < 2) ? Abase : Bbase;                                     \
        const bf16* _src = _mb + (size_t)row * KROW + _ko + (reg & 1) * 32 + c * 8;      \
        int _dst = _slot * SLOTSZ + reg * 4096 + o * 8;                                  \
        __builtin_amdgcn_global_load_lds((const AS1 void*)_src,                          \
            (AS3 void*)(&lds[_dst]), 16, 0, 0);                                          \
    }                                                                                    \
} while (0)

    // MODE 1: fold rowscale — psum loads issued BEFORE stages; prologue vmcnt(8)
    // drains psum + slot 0 and leaves slot 1 in flight (ledger preserved).
    if constexpr (MODE == 1) {
        if (tid < 128) {
            int row = bm * 128 + tid;
            float s = 0.f;
#pragma unroll
            for (int h = 0; h < NHEADS; h++) s += psum[(size_t)row * NHEADS + h];
            srs[tid] = rsqrtf(s * (1.0f / DINNER) + 1.1920928955078125e-07f);
        }
    }

    f32x4 acc[4][4];
#pragma unroll
    for (int i = 0; i < 4; i++)
#pragma unroll
        for (int j = 0; j < 4; j++) acc[i][j] = (f32x4){0.f, 0.f, 0.f, 0.f};

    STAGE8(0); STAGE8(1);
    asm volatile("s_waitcnt vmcnt(8)" ::: "memory");   // slot 0 landed (slot 1 in flight)
    __builtin_amdgcn_s_barrier();

    for (int p = 0; p < NSLICE; ++p) {
        const bf16* base_ = &lds[(p & 1) * SLOTSZ];
        bf16x8 af[4][2], bfv[4][2];
#pragma unroll
        for (int i = 0; i < 4; ++i) {
            int row = wm + i * 16 + lml;
#pragma unroll
            for (int kh = 0; kh < 2; ++kh)
                af[i][kh] = *reinterpret_cast<const bf16x8*>(&base_[kh * 4096 + lds_elem(row, kc)]);
        }
#pragma unroll
        for (int j = 0; j < 4; ++j) {
            int row = wn + j * 16 + lml;
#pragma unroll
            for (int kh = 0; kh < 2; ++kh)
                bfv[j][kh] = *reinterpret_cast<const bf16x8*>(&base_[(2 + kh) * 4096 + lds_elem(row, kc)]);
        }
        asm volatile("s_waitcnt lgkmcnt(0)" ::: "memory");
        __builtin_amdgcn_sched_barrier(0);
        __builtin_amdgcn_s_barrier();        // slot p fully consumed by all waves
        if (p + 2 < NSLICE) STAGE8(p + 2);   // refill the just-freed slot
#pragma unroll
        for (int kh = 0; kh < 2; ++kh)
#pragma unroll
            for (int i = 0; i < 4; ++i)
#pragma unroll
                for (int j = 0; j < 4; ++j)
                    acc[i][j] = __builtin_amdgcn_mfma_f32_16x16x32_bf16(af[i][kh], bfv[j][kh], acc[i][j], 0, 0, 0);
        if (p + 1 < NSLICE) {
            if (p + 2 < NSLICE) { asm volatile("s_waitcnt vmcnt(8)" ::: "memory"); }
            else                { asm volatile("s_waitcnt vmcnt(0)" ::: "memory"); }
            __builtin_amdgcn_s_barrier();
        }
    }
#undef STAGE8

    const int rbase = (lane >> 4) * 4;
#pragma unroll
    for (int i = 0; i < 4; i++) {
#pragma unroll
        for (int j = 0; j < 4; j++) {
            int col = bn * 128 + wn + j * 16 + lml;
            if constexpr (MODE == 0) {
                bool isZ = (col < ZDIM);
                bool isG = (col >= NGATE0) && (col < NGATE0 + DINNER);
                bool isDT = (col >= 4096) && (col < ZDIM);
                if (!isZ && !isG) continue;
#pragma unroll
                for (int r = 0; r < 4; r++) {
                    int row = bm * 128 + wm + i * 16 + rbase + r;
                    float v = acc[i][j][r];
                    if (isZ) {
                        z[(size_t)row * ZDIM + col] = (bf16)v;
                        if (isDT) {
                            int h = col - 4096;
                            float v2 = v + dparam[h];
                            float sp = (v2 > 20.f) ? v2 : log1pf(expf(v2));
                            lab[(size_t)row * NHEADS + h] = -sp * fabsf(v);
                        }
                    }
                    if (isG) {
                        g[(size_t)row * GPAD + (col - NGATE0)] = (bf16)v;
                    }
                }
            } else {
                int row0 = bm * 128 + wm + i * 16 + rbase;
                int l0 = wm + i * 16 + rbase;
#pragma unroll
                for (int r = 0; r < 4; r++)
                    c32[(size_t)(row0 + r) * 1024 + col] = acc[i][j][r] * srs[l0 + r];
            }
        }
    }
}

// ================= chunked scan, SSD matmul form, conv+SiLU fused in =================
__global__ __launch_bounds__(256) void chunk_state_kernel(
    const bf16* __restrict__ zz,   // z base (x cols 0..2047, B at 2048+h*64), stride ZDIM
    const float* __restrict__ conv_w, const float* __restrict__ conv_b,
    const float* __restrict__ la,  // [BL][16] log a
    bf16* __restrict__ S,          // [B][NCHUNK][NHEADS][128*64]
    float* __restrict__ Adec)      // [B][NHEADS][NCHUNK] = exp(Ls_Q)
{
    __shared__ __align__(16) bf16 xt[HEADDIM * QCHUNK]; // [d][t] swizzled
    __shared__ __align__(16) bf16 bw[DSTATE * QCHUNK];  // [s][t] swizzled, weighted
    __shared__ float Ls[QCHUNK];
    const int blk = blockIdx.x;
    const int h = blk & 15, c = (blk >> 4) & 63, b = blk >> 10;
    const int tid = threadIdx.x, lane = tid & 63, w = tid >> 6;
    const size_t row0 = (size_t)b * LSEQ + (size_t)c * QCHUNK;
    const bf16* zxg = zz + row0 * ZDIM + h * HEADDIM;
    const bf16* Bg  = zz + row0 * ZDIM + DINNER + h * DSTATE;

    // ---- fused conv+SiLU: thread = (tg 4 t-rows) x (dg8 8 d-cols) ----
    const int tg = (tid >> 4) * 4;
    const int dg8 = (tid & 15) * 8;
    float wv[8][4], xa[4][8];
#pragma unroll
    for (int e = 0; e < 8; e++) {
        float4 w4 = *reinterpret_cast<const float4*>(conv_w + (size_t)(h * HEADDIM + dg8 + e) * 4);
        wv[e][0] = w4.x; wv[e][1] = w4.y; wv[e][2] = w4.z; wv[e][3] = w4.w;
        float bb = conv_b[h * HEADDIM + dg8 + e];
#pragma unroll
        for (int tt = 0; tt < 4; tt++) xa[tt][e] = bb;
    }
#pragma unroll
    for (int r = 0; r < 7; r++) {
        int lrow = c * QCHUNK + tg + r - 3;      // local index within this batch sequence
        if (lrow >= 0) {
            bf16x8 zv = *reinterpret_cast<const bf16x8*>(zxg + (ptrdiff_t)(tg + r - 3) * ZDIM + dg8);
#pragma unroll
            for (int tt = 0; tt < 4; tt++) {
                int k = r - tt;
                if (k >= 0 && k < 4) {
#pragma unroll
                    for (int e = 0; e < 8; e++)
                        xa[tt][e] = fmaf((float)zv[e], wv[e][k], xa[tt][e]);
                }
            }
        }
    }
#pragma unroll
    for (int tt = 0; tt < 4; tt++)
#pragma unroll
        for (int e = 0; e < 8; e++)
            xa[tt][e] = xa[tt][e] / (1.f + expf(-xa[tt][e]));

    const int t = tid >> 2, sseg = (tid & 3) * 16;
    bf16x8 br[2];
#pragma unroll
    for (int q = 0; q < 2; q++)
        br[q] = *reinterpret_cast<const bf16x8*>(Bg + (size_t)t * ZDIM + sseg + q * 8);

    if (w == 0) {
        float v = la[(row0 + lane) * NHEADS + h];
#pragma unroll
        for (int off = 1; off < 64; off <<= 1) { float o = __shfl_up(v, off); if (lane >= off) v += o; }
        Ls[lane] = v;
        if (lane == 63) Adec[((size_t)b * NHEADS + h) * NCHUNK + c] = __expf(v);
    }
    __syncthreads();
    const float wt = __expf(Ls[QCHUNK - 1] - Ls[t]);
#pragma unroll
    for (int tt = 0; tt < 4; tt++) {
        int t2 = tg + tt;
#pragma unroll
        for (int e = 0; e < 8; e++) {
            int d = dg8 + e;
            xt[d * 64 + (((t2 >> 3) ^ (d & 7)) << 3) + (t2 & 7)] = (bf16)xa[tt][e];
        }
    }
    const int tb = t >> 3, ti = t & 7;
#pragma unroll
    for (int q = 0; q < 2; q++)
#pragma unroll
        for (int j = 0; j < 8; j++) {
            int s = sseg + q * 8 + j;
            bw[s * 64 + ((tb ^ (s & 7)) << 3) + ti] = (bf16)((float)br[q][j] * wt);
        }
    __syncthreads();

    f32x4 acc[2][4];
#pragma unroll
    for (int i = 0; i < 2; i++)
#pragma unroll
        for (int j = 0; j < 4; j++) acc[i][j] = (f32x4){0.f, 0.f, 0.f, 0.f};
#pragma unroll
    for (int kk = 0; kk < 2; kk++) {
        const int kb = kk * 4 + (lane >> 4);
        bf16x8 af[2], bf2[4];
#pragma unroll
        for (int i = 0; i < 2; i++) {
            int d = w * 32 + i * 16 + (lane & 15);
            af[i] = *reinterpret_cast<const bf16x8*>(&xt[d * 64 + ((kb ^ (d & 7)) << 3)]);
        }
#pragma unroll
        for (int j = 0; j < 4; j++) {
            int s = j * 16 + (lane & 15);
            bf2[j] = *reinterpret_cast<const bf16x8*>(&bw[s * 64 + ((kb ^ (s & 7)) << 3)]);
        }
#pragma unroll
        for (int i = 0; i < 2; i++)
#pragma unroll
            for (int j = 0; j < 4; j++)
                acc[i][j] = __builtin_amdgcn_mfma_f32_16x16x32_bf16(af[i], bf2[j], acc[i][j], 0, 0, 0);
    }
    bf16* Sg = S + ((size_t)(b * NCHUNK + c) * NHEADS + h) * (HEADDIM * DSTATE);
    const int rr = (lane >> 4) * 4, ccol = lane & 15;
#pragma unroll
    for (int i = 0; i < 2; i++)
#pragma unroll
        for (int j = 0; j < 4; j++)
#pragma unroll
            for (int r = 0; r < 4; r++)
                Sg[(w * 32 + i * 16 + rr + r) * 64 + j * 16 + ccol] = (bf16)acc[i][j][r];
}

// Pass 1b: inter-chunk carry, in-place: S_c -> H_c (state at chunk START).
__global__ void chunk_carry_kernel(bf16* S, const float* __restrict__ A)
{
    int gid = blockIdx.x * 256 + threadIdx.x;
    if (gid >= BATCH * NHEADS * HEADDIM * DSTATE) return;
    int es = gid & (HEADDIM * DSTATE - 1);
    int h  = (gid >> 13) & (NHEADS - 1);
    int b  = gid >> 17;
    const float* Ab = A + ((size_t)b * NHEADS + h) * NCHUNK;
    float hstate = 0.f;
    size_t stride = (size_t)NHEADS * HEADDIM * DSTATE;
    bf16* p = S + ((size_t)b * NCHUNK * NHEADS + h) * (HEADDIM * DSTATE) + es;
    for (int c = 0; c < NCHUNK; ++c) {
        float sv = (float)*p;
        *p = (bf16)hstate;
        hstate = fmaf(Ab[c], hstate, sv);
        p += stride;
    }
}

// Pass 2: Y^T[d][t] = [Xt | H] @ [MG | P.C]^T, conv+SiLU fused; epilogue applies the
// gate (v = y*sigmoid(g), written in-place over g) and emits per-(row,head) sum(v^2).
__global__ __launch_bounds__(256) void chunk_y_kernel(
    bf16* __restrict__ gv,          // [BL][GPAD]: gate pre-act in, gated v out (in-place)
    const bf16* __restrict__ zz,    // z base (x cols + B/C), stride ZDIM
    const float* __restrict__ conv_w, const float* __restrict__ conv_b,
    const float* __restrict__ la,   // [BL][16] log a
    const bf16* __restrict__ H,     // [B][NCHUNK][NHEADS][128*64] chunk-start state
    float* __restrict__ psum)       // [BL][NHEADS] per-head sum(v^2)
{
    __shared__ __align__(16) bf16 bc[QCHUNK * 128];    // B | C, later MG[64][128]
    __shared__ __align__(16) bf16 xt[HEADDIM * QCHUNK];
    __shared__ __align__(16) bf16 hl[HEADDIM * DSTATE];
    __shared__ float Ls[QCHUNK];
    __shared__ float wsum[4][QCHUNK];
    const int blk = blockIdx.x;
    const int h = blk & 15, c = (blk >> 4) & 63, b = blk >> 10;
    const int tid = threadIdx.x, lane = tid & 63, w = tid >> 6;
    const size_t row0 = (size_t)b * LSEQ + (size_t)c * QCHUNK;
    bf16* gg = gv + row0 * GPAD + h * HEADDIM;
    const bf16* zxg = zz + row0 * ZDIM + h * HEADDIM;
    const bf16* Bg = zz + row0 * ZDIM + DINNER + h * DSTATE;
    const bf16* Cg = Bg + NHEADS * DSTATE;
    const bf16* Hg = H + ((size_t)(b * NCHUNK + c) * NHEADS + h) * (HEADDIM * DSTATE);

#pragma unroll
    for (int it = 0; it < 2; it++) {
        int idx = it * 256 + tid;
        int row = idx >> 3, p = idx & 7;
        int sc = (p ^ (row & 7)) << 3;
        __builtin_amdgcn_global_load_lds((const AS1 void*)(Bg + (size_t)row * ZDIM + sc),
                                         (AS3 void*)(&bc[idx * 8]), 16, 0, 0);
        __builtin_amdgcn_global_load_lds((const AS1 void*)(Cg + (size_t)row * ZDIM + sc),
                                         (AS3 void*)(&bc[4096 + idx * 8]), 16, 0, 0);
    }
#pragma unroll
    for (int it = 0; it < 4; it++) {
        int idx = it * 256 + tid;
        int d = idx >> 3, p = idx & 7;
        __builtin_amdgcn_global_load_lds((const AS1 void*)(Hg + d * 64 + ((p ^ (d & 7)) << 3)),
                                         (AS3 void*)(&hl[idx * 8]), 16, 0, 0);
    }

    // ---- fused conv+SiLU ----
    const int tg = (tid >> 4) * 4;
    const int dg8 = (tid & 15) * 8;
    float wv[8][4], xa[4][8];
#pragma unroll
    for (int e = 0; e < 8; e++) {
        float4 w4 = *reinterpret_cast<const float4*>(conv_w + (size_t)(h * HEADDIM + dg8 + e) * 4);
        wv[e][0] = w4.x; wv[e][1] = w4.y; wv[e][2] = w4.z; wv[e][3] = w4.w;
        float bb = conv_b[h * HEADDIM + dg8 + e];
#pragma unroll
        for (int tt = 0; tt < 4; tt++) xa[tt][e] = bb;
    }
#pragma unroll
    for (int r = 0; r < 7; r++) {
        int lrow = c * QCHUNK + tg + r - 3;
        if (lrow >= 0) {
            bf16x8 zv = *reinterpret_cast<const bf16x8*>(zxg + (ptrdiff_t)(tg + r - 3) * ZDIM + dg8);
#pragma unroll
            for (int tt = 0; tt < 4; tt++) {
                int k = r - tt;
                if (k >= 0 && k < 4) {
#pragma unroll
                    for (int e = 0; e < 8; e++)
                        xa[tt][e] = fmaf((float)zv[e], wv[e][k], xa[tt][e]);
                }
            }
        }
    }
#pragma unroll
    for (int tt = 0; tt < 4; tt++)
#pragma unroll
        for (int e = 0; e < 8; e++)
            xa[tt][e] = xa[tt][e] / (1.f + expf(-xa[tt][e]));

    const int t = tid >> 2, sseg = (tid & 3) * 16;
    if (w == 0) {
        float v = la[(row0 + lane) * NHEADS + h];
#pragma unroll
        for (int off = 1; off < 64; off <<= 1) { float o = __shfl_up(v, off); if (lane >= off) v += o; }
        Ls[lane] = v;
    }
    __syncthreads();

#pragma unroll
    for (int tt = 0; tt < 4; tt++) {
        int t2 = tg + tt;
#pragma unroll
        for (int e = 0; e < 8; e++) {
            int d = dg8 + e;
            xt[d * 64 + (((t2 >> 3) ^ (d & 7)) << 3) + (t2 & 7)] = (bf16)xa[tt][e];
        }
    }

    // MFMA1: G[t][t'] = sum_s C[t,s] B[t',s]
    f32x4 g[4];
#pragma unroll
    for (int j = 0; j < 4; j++) g[j] = (f32x4){0.f, 0.f, 0.f, 0.f};
#pragma unroll
    for (int kk = 0; kk < 2; kk++) {
        const int kb = kk * 4 + (lane >> 4);
        const int tA = w * 16 + (lane & 15);
        bf16x8 ca = *reinterpret_cast<const bf16x8*>(&bc[4096 + tA * 64 + ((kb ^ (tA & 7)) << 3)]);
#pragma unroll
        for (int j = 0; j < 4; j++) {
            int tB = j * 16 + (lane & 15);
            bf16x8 bb = *reinterpret_cast<const bf16x8*>(&bc[tB * 64 + ((kb ^ (tB & 7)) << 3)]);
            g[j] = __builtin_amdgcn_mfma_f32_16x16x32_bf16(ca, bb, g[j], 0, 0, 0);
        }
    }
    bf16x8 cr[2];
#pragma unroll
    for (int q = 0; q < 2; q++) {
        int sblk = (sseg >> 3) + q;
        cr[q] = *reinterpret_cast<const bf16x8*>(&bc[4096 + t * 64 + ((sblk ^ (t & 7)) << 3)]);
    }
    const float pscale = __expf(Ls[t]);
    __syncthreads();

    {
        const int tpbase = lane & 15;
        const int tgbase = w * 16 + (lane >> 4) * 4;
        float lst[4];
#pragma unroll
        for (int r = 0; r < 4; r++) lst[r] = Ls[tgbase + r];
#pragma unroll
        for (int j = 0; j < 4; j++) {
            int tp = j * 16 + tpbase;
            float lstp = Ls[tp];
#pragma unroll
            for (int r = 0; r < 4; r++) {
                int tg2 = tgbase + r;
                float mg = (tp <= tg2) ? g[j][r] * __expf(lst[r] - lstp) : 0.f;
                bc[tg2 * 128 + (((tp >> 3) ^ (tg2 & 7)) << 3) + (tp & 7)] = (bf16)mg;
            }
        }
    }
#pragma unroll
    for (int q = 0; q < 2; q++) {
        int sblk = (sseg >> 3) + q;
        bf16x8 o;
#pragma unroll
        for (int j = 0; j < 8; j++) o[j] = (bf16)((float)cr[q][j] * pscale);
        *reinterpret_cast<bf16x8*>(&bc[t * 128 + ((8 + (sblk ^ (t & 7))) << 3)]) = o;
    }
    __syncthreads();

    f32x4 acc[2][4];
#pragma unroll
    for (int i = 0; i < 2; i++)
#pragma unroll
        for (int j = 0; j < 4; j++) acc[i][j] = (f32x4){0.f, 0.f, 0.f, 0.f};
#pragma unroll
    for (int kk = 0; kk < 4; kk++) {
        const int kb = kk * 4 + (lane >> 4);
        bf16x8 af[2];
#pragma unroll
        for (int i = 0; i < 2; i++) {
            int d = w * 32 + i * 16 + (lane & 15);
            if (kk < 2)
                af[i] = *reinterpret_cast<const bf16x8*>(&xt[d * 64 + ((kb ^ (d & 7)) << 3)]);
            else
                af[i] = *reinterpret_cast<const bf16x8*>(&hl[d * 64 + (((kb - 8) ^ (d & 7)) << 3)]);
        }
#pragma unroll
        for (int j = 0; j < 4; j++) {
            int tt = j * 16 + (lane & 15);
            bf16x8 b2 = *reinterpret_cast<const bf16x8*>(&bc[tt * 128 + ((kb ^ (tt & 7)) << 3)]);
#pragma unroll
            for (int i = 0; i < 2; i++)
                acc[i][j] = __builtin_amdgcn_mfma_f32_16x16x32_bf16(af[i], b2, acc[i][j], 0, 0, 0);
        }
    }

    // ---- epilogue: v = y * sigmoid(gate); write v in-place; accumulate row sum(v^2) ----
    float ps[4] = {0.f, 0.f, 0.f, 0.f};
#pragma unroll
    for (int i = 0; i < 2; i++)
#pragma unroll
        for (int j = 0; j < 4; j++) {
            int d0 = w * 32 + i * 16 + (lane >> 4) * 4;
            int tt = j * 16 + (lane & 15);
            bf16x4 gt = *reinterpret_cast<const bf16x4*>(gg + (size_t)tt * GPAD + d0);
            bf16x4 o;
#pragma unroll
            for (int r = 0; r < 4; r++) {
                float gf = (float)gt[r];
                float vv = acc[i][j][r] / (1.f + expf(-gf));
                o[r] = (bf16)vv;
                ps[j] = fmaf(vv, vv, ps[j]);
            }
            *reinterpret_cast<bf16x4*>(gg + (size_t)tt * GPAD + d0) = o;
        }
    // reduce over lane>>4 (4 lanes share same rows within a wave)
#pragma unroll
    for (int j = 0; j < 4; j++) {
        ps[j] += __shfl_xor(ps[j], 16);
        ps[j] += __shfl_xor(ps[j], 32);
    }
    if ((lane >> 4) == 0) {
#pragma unroll
        for (int j = 0; j < 4; j++) wsum[w][j * 16 + (lane & 15)] = ps[j];
    }
    __syncthreads();
    if (tid < QCHUNK) {
        float tot = wsum[0][tid] + wsum[1][tid] + wsum[2][tid] + wsum[3][tid];
        psum[(row0 + tid) * NHEADS + h] = tot;
    }
}

// ---------------- launch ----------------
extern "C" void kernel_launch(void* const* d_in, const int* in_sizes, int n_in,
                              void* d_out, int out_size, void* d_ws, size_t ws_size,
                              hipStream_t stream)
{
    const float* u      = (const float*)d_in[0];
    const float* W_in   = (const float*)d_in[1];
    const float* conv_w = (const float*)d_in[2];
    const float* conv_b = (const float*)d_in[3];
    const float* dparam = (const float*)d_in[4];
    const float* W_gate = (const float*)d_in[5];
    const float* norm_w = (const float*)d_in[6];
    const float* W_out  = (const float*)d_in[7];
    float* out = (float*)d_out;

    char* ws = (char*)d_ws;
    size_t off = 0;
    auto alloc = [&](size_t bytes) {
        void* p = ws + off;
        off += (bytes + 255) & ~(size_t)255;
        return p;
    };
    // total ws use: ~174 MB (padded strides)
    bf16*  u_bf  = (bf16*) alloc((size_t)BLROWS * UPAD * 2);     // 17.8 MB
    bf16*  Wt_f  = (bf16*) alloc((size_t)6288 * UPAD * 2);       // 13.7 MB (W_in | W_gate | pad)
    bf16*  Wt_o  = (bf16*) alloc((size_t)DMODEL * GPAD * 2);     // 4.3 MB (norm_w folded in)
    bf16*  z     = (bf16*) alloc((size_t)BLROWS * ZDIM * 2);     // 67.4 MB
    bf16*  g     = (bf16*) alloc((size_t)BLROWS * GPAD * 2);     // 34.6 MB (gate in, v in-place)
    float* lab   = (float*)alloc((size_t)BLROWS * NHEADS * 4);   // 0.5 MB (log a, written by GEMM)
    bf16*  S     = (bf16*) alloc((size_t)BATCH * NCHUNK * NHEADS * HEADDIM * DSTATE * 2); // 33.6 MB
    float* Adec  = (float*)alloc((size_t)BATCH * NHEADS * NCHUNK * 4);                    // 8 KB
    float* psum  = (float*)alloc((size_t)BLROWS * NHEADS * 4);   // 0.5 MB
    (void)ws_size; (void)in_sizes; (void)n_in; (void)out_size;

    // merged prologue: cvt_pad + W_in/W_gate/W_out transposes (norm_w folded into Wt_o)
    prep_kernel<<<PREP_WO, 256, 0, stream>>>(u, W_in, W_gate, W_out, norm_w, u_bf, Wt_f, Wt_o);

    // fused z|g GEMM (+inline la): M=8192 (64 bm), K=1024 @UPAD (16 K-tiles of 64), N=6272
    gemm_db3_kernel<16, UPAD, 0, 49><<<64 * 49, 256, 0, stream>>>(
        u_bf, Wt_f, z, g, lab, dparam, nullptr, nullptr);

    // chunked scan (SSD matmul form) with conv+SiLU fused; chunk_y also applies the gate
    chunk_state_kernel<<<BATCH * NCHUNK * NHEADS, 256, 0, stream>>>(z, conv_w, conv_b, lab, S, Adec);
    chunk_carry_kernel<<<(BATCH * NHEADS * HEADDIM * DSTATE) / 256, 256, 0, stream>>>(S, Adec);
    chunk_y_kernel<<<BATCH * NCHUNK * NHEADS, 256, 0, stream>>>(g, z, conv_w, conv_b, lab, S, psum);

    // out = (v * rs) @ (norm_w-folded W_out), rowscale computed in-kernel from psum
    gemm_db3_kernel<32, GPAD, 1, 8><<<64 * 8, 256, 0, stream>>>(
        g, Wt_o, nullptr, nullptr, nullptr, nullptr, psum, out);
}